// Round 5
// baseline (628.246 us; speedup 1.0000x reference)
//
#include <hip/hip_runtime.h>

// ---------------------------------------------------------------------------
// Multiheaded_GRUMix_Attention on MI355X (gfx950). Inputs f32, output f32.
//
// R5: r4 proved inputs are f32 (NaN vanished on f32 interpretation); output
// must also be f32 per harness doc (r4's bf16 writes -> error 2.03 ~ garbage
// of correct scale). This round: f32 I/O; bf16 MFMA for smooth GEMM paths;
// f32 split-bf16 (hi+lo, 3 MFMAs) for the chaotic mu/sigma path, since
// sigma ~ 5e-4 vs position grid 2e-3 makes location attention delta-like.
//
// Pipeline: convert(7 tensors f32->bf16) -> Qh/Kh/Vh GEMMs (bf16) ->
//   Xg = relu(Q@Wpos+bpos) split-GEMM (f32 out) -> mix/len (f32) ->
//   fused GRU (split-bf16 MFMA, f32 mu/sigma) ->
//   fused attention (QK^T bf16 + f32 dual softmax/gauss + mix + PV) ->
//   out = att @ Wc (bf16 MFMA, f32 out).
// Workspace ~70 MB.
// ---------------------------------------------------------------------------

typedef __bf16 bf16;
typedef __bf16 bfx8 __attribute__((ext_vector_type(8)));
typedef float v4f __attribute__((ext_vector_type(4)));

__device__ inline float sigm(float x) { return 1.0f / (1.0f + expf(-x)); }

__device__ inline v4f mfma16(bfx8 a, bfx8 b, v4f c) {
    return __builtin_amdgcn_mfma_f32_16x16x32_bf16(a, b, c, 0, 0, 0);
}

// load 8 f32 and split each into bf16 hi + bf16 lo (hi = rne(x), lo = rne(x-hi))
__device__ inline void split8(const float* __restrict__ p, bfx8& hi, bfx8& lo) {
    float4 x = *(const float4*)p;
    float4 y = *(const float4*)(p + 4);
    float v[8] = {x.x, x.y, x.z, x.w, y.x, y.y, y.z, y.w};
#pragma unroll
    for (int j = 0; j < 8; ++j) {
        bf16 h = (bf16)v[j];
        hi[j] = h;
        lo[j] = (bf16)(v[j] - (float)h);
    }
}

// ---------------------------------------------------------------------------
// Batched f32 -> bf16 converter for the 7 MFMA-fed tensors.
// ---------------------------------------------------------------------------
#define NCV 7
struct ConvArgs {
    const float* src[NCV];
    bf16* dst[NCV];
    long n[NCV];
    int pref[NCV + 1];   // 2048-element chunk prefix
};

__global__ __launch_bounds__(256) void convert_kernel(ConvArgs a) {
    int b = blockIdx.x;
    int t = 0;
    while (t < NCV - 1 && b >= a.pref[t + 1]) ++t;
    const long n = a.n[t];
    const long i0 = (long)(b - a.pref[t]) * 2048 + threadIdx.x * 8;
    bf16* dst = a.dst[t];
    const float* src = a.src[t];
    if (i0 + 8 <= n) {
        float4 x = *(const float4*)(src + i0);
        float4 y = *(const float4*)(src + i0 + 4);
        bfx8 o;
        o[0] = (bf16)x.x; o[1] = (bf16)x.y; o[2] = (bf16)x.z; o[3] = (bf16)x.w;
        o[4] = (bf16)y.x; o[5] = (bf16)y.y; o[6] = (bf16)y.z; o[7] = (bf16)y.w;
        *(bfx8*)(dst + i0) = o;
    } else {
        for (long i = i0; i < n; ++i) dst[i] = (bf16)src[i];
    }
}

// ---------------------------------------------------------------------------
// bf16 MFMA GEMM, C[M,N] = A[M,K]@B[K,N], OutT in {bf16,float}.
// BM=BN=64, BK=32; 4 waves x (2x2 16x16 tiles). LDS rows 72 (16B-aligned).
// ---------------------------------------------------------------------------
template <typename OutT>
__global__ __launch_bounds__(256) void gemm_nn(
    const bf16* __restrict__ A, const bf16* __restrict__ B,
    OutT* __restrict__ C, int K, int lda, int ldb, int ldc) {
    __shared__ bf16 As[64][72];
    __shared__ bf16 Bs[64][72];

    const int mbase = blockIdx.x * 64, nbase = blockIdx.y * 64;
    const int t = threadIdx.x;
    const int wave = t >> 6, lane = t & 63;
    const int quad = lane >> 4, c = lane & 15;
    const int wrow = (wave >> 1) * 32, wcol = (wave & 1) * 32;

    const v4f zero4 = {0.f, 0.f, 0.f, 0.f};
    v4f acc[2][2];
    acc[0][0] = zero4; acc[0][1] = zero4; acc[1][0] = zero4; acc[1][1] = zero4;

    const int ar = t >> 2, ach = t & 3;
    const int bk = t >> 3, bch = t & 7;

    for (int k0 = 0; k0 < K; k0 += 32) {
        bfx8 va = *(const bfx8*)(A + (long)(mbase + ar) * lda + k0 + ach * 8);
        *(bfx8*)(&As[ar][ach * 8]) = va;
        bfx8 vb = *(const bfx8*)(B + (long)(k0 + bk) * ldb + nbase + bch * 8);
#pragma unroll
        for (int j = 0; j < 8; ++j) Bs[bch * 8 + j][bk] = vb[j];
        __syncthreads();

        bfx8 a0 = *(const bfx8*)(&As[wrow + c][quad * 8]);
        bfx8 a1 = *(const bfx8*)(&As[wrow + 16 + c][quad * 8]);
        bfx8 b0 = *(const bfx8*)(&Bs[wcol + c][quad * 8]);
        bfx8 b1 = *(const bfx8*)(&Bs[wcol + 16 + c][quad * 8]);
        acc[0][0] = mfma16(a0, b0, acc[0][0]);
        acc[0][1] = mfma16(a0, b1, acc[0][1]);
        acc[1][0] = mfma16(a1, b0, acc[1][0]);
        acc[1][1] = mfma16(a1, b1, acc[1][1]);
        __syncthreads();
    }

#pragma unroll
    for (int tm = 0; tm < 2; ++tm)
#pragma unroll
        for (int tn = 0; tn < 2; ++tn)
#pragma unroll
            for (int i = 0; i < 4; ++i) {
                int row = mbase + wrow + tm * 16 + quad * 4 + i;
                int col = nbase + wcol + tn * 16 + c;
                C[(long)row * ldc + col] = (OutT)acc[tm][tn][i];
            }
}

// ---------------------------------------------------------------------------
// Split-bf16 GEMM: C = relu(A@B + bias), all f32 I/O, f32-grade accuracy.
// acc += Ah*Bh + Ah*Bl + Al*Bh (AlBl dropped, ~2^-18 rel).
// ---------------------------------------------------------------------------
__global__ __launch_bounds__(256) void gemm_split_relu(
    const float* __restrict__ A, const float* __restrict__ B,
    const float* __restrict__ bias, float* __restrict__ C,
    int K, int lda, int ldb, int ldc) {
    __shared__ bf16 Ah[64][72], Al[64][72];
    __shared__ bf16 Bh[64][72], Bl[64][72];

    const int mbase = blockIdx.x * 64, nbase = blockIdx.y * 64;
    const int t = threadIdx.x;
    const int wave = t >> 6, lane = t & 63;
    const int quad = lane >> 4, c = lane & 15;
    const int wrow = (wave >> 1) * 32, wcol = (wave & 1) * 32;

    const v4f zero4 = {0.f, 0.f, 0.f, 0.f};
    v4f acc[2][2];
    acc[0][0] = zero4; acc[0][1] = zero4; acc[1][0] = zero4; acc[1][1] = zero4;

    const int ar = t >> 2, ach = t & 3;
    const int bk = t >> 3, bch = t & 7;

    for (int k0 = 0; k0 < K; k0 += 32) {
        bfx8 h, l;
        split8(A + (long)(mbase + ar) * lda + k0 + ach * 8, h, l);
        *(bfx8*)(&Ah[ar][ach * 8]) = h;
        *(bfx8*)(&Al[ar][ach * 8]) = l;
        split8(B + (long)(k0 + bk) * ldb + nbase + bch * 8, h, l);
#pragma unroll
        for (int j = 0; j < 8; ++j) { Bh[bch * 8 + j][bk] = h[j]; Bl[bch * 8 + j][bk] = l[j]; }
        __syncthreads();

        bfx8 ah0 = *(const bfx8*)(&Ah[wrow + c][quad * 8]);
        bfx8 ah1 = *(const bfx8*)(&Ah[wrow + 16 + c][quad * 8]);
        bfx8 al0 = *(const bfx8*)(&Al[wrow + c][quad * 8]);
        bfx8 al1 = *(const bfx8*)(&Al[wrow + 16 + c][quad * 8]);
        bfx8 bh0 = *(const bfx8*)(&Bh[wcol + c][quad * 8]);
        bfx8 bh1 = *(const bfx8*)(&Bh[wcol + 16 + c][quad * 8]);
        bfx8 bl0 = *(const bfx8*)(&Bl[wcol + c][quad * 8]);
        bfx8 bl1 = *(const bfx8*)(&Bl[wcol + 16 + c][quad * 8]);
        acc[0][0] = mfma16(ah0, bh0, acc[0][0]);
        acc[0][0] = mfma16(ah0, bl0, acc[0][0]);
        acc[0][0] = mfma16(al0, bh0, acc[0][0]);
        acc[0][1] = mfma16(ah0, bh1, acc[0][1]);
        acc[0][1] = mfma16(ah0, bl1, acc[0][1]);
        acc[0][1] = mfma16(al0, bh1, acc[0][1]);
        acc[1][0] = mfma16(ah1, bh0, acc[1][0]);
        acc[1][0] = mfma16(ah1, bl0, acc[1][0]);
        acc[1][0] = mfma16(al1, bh0, acc[1][0]);
        acc[1][1] = mfma16(ah1, bh1, acc[1][1]);
        acc[1][1] = mfma16(ah1, bl1, acc[1][1]);
        acc[1][1] = mfma16(al1, bh1, acc[1][1]);
        __syncthreads();
    }

#pragma unroll
    for (int tm = 0; tm < 2; ++tm)
#pragma unroll
        for (int tn = 0; tn < 2; ++tn)
#pragma unroll
            for (int i = 0; i < 4; ++i) {
                int row = mbase + wrow + tm * 16 + quad * 4 + i;
                int col = nbase + wcol + tn * 16 + c;
                float v = acc[tm][tn][i] + bias[col];
                C[(long)row * ldc + col] = fmaxf(v, 0.f);
            }
}

// ---------------------------------------------------------------------------
// mix gate + mask lengths: one wave per (n,q) row (8192 rows), f32.
// ---------------------------------------------------------------------------
__global__ __launch_bounds__(256) void mix_len_kernel(
    const float* __restrict__ Q, const int* __restrict__ mask,
    const float* __restrict__ mix_w, const float* __restrict__ mix_b,
    float* __restrict__ mixv, float* __restrict__ stepv, float* __restrict__ lenv) {
    int row = blockIdx.x * 4 + (threadIdx.x >> 6);
    int lane = threadIdx.x & 63;
    float4 qa = *(const float4*)(Q + (long)row * 512 + lane * 8);
    float4 qb = *(const float4*)(Q + (long)row * 512 + lane * 8 + 4);
    float4 wa = *(const float4*)(mix_w + lane * 8);
    float4 wb = *(const float4*)(mix_w + lane * 8 + 4);
    float dot = qa.x * wa.x + qa.y * wa.y + qa.z * wa.z + qa.w * wa.w +
                qb.x * wb.x + qb.y * wb.y + qb.z * wb.z + qb.w * wb.w;
    const int* mrow = mask + (long)row * 512 + lane * 8;
    float ms = 0.f;
#pragma unroll
    for (int j = 0; j < 8; ++j) ms += (float)mrow[j];
#pragma unroll
    for (int o = 32; o > 0; o >>= 1) {
        dot += __shfl_xor(dot, o);
        ms += __shfl_xor(ms, o);
    }
    if (lane == 0) {
        mixv[row] = sigm(dot + mix_b[0]);
        lenv[row] = ms;
        stepv[row] = 1.0f / fmaxf(1.0f, ms - 1.0f);
    }
}

// ---------------------------------------------------------------------------
// Fused GRU with split-bf16 gate GEMMs (f32-grade): per block 64 rows of one
// (n,hd). Wave computes all 192 gate cols for its 16 rows; gates r/z/n for
// (row,d) live in the same lane (tiles t4, t4+4, t4+8). mu/sigma in f32.
// ---------------------------------------------------------------------------
__global__ __launch_bounds__(256) void gru_fused_kernel(
    const float* __restrict__ Xg, const float* __restrict__ hp,
    const float* __restrict__ gwi, const float* __restrict__ gwh,
    const float* __restrict__ gbi, const float* __restrict__ gbh,
    const float* __restrict__ pa, const float* __restrict__ Wsigma,
    const float* __restrict__ Wrho,
    const float* __restrict__ lenv, const float* __restrict__ stepv,
    float* __restrict__ muv, float* __restrict__ sigv) {
    __shared__ bf16 Wh[192][72], Wl[192][72];   // transposed weight [n][k]
    __shared__ float biL[384];

    const int b = blockIdx.x;                 // 1024 = nh(128) * qb(8)
    const int qb = b & 7, nh = b >> 3, hd = nh & 7, n = nh >> 3;
    const int t = threadIdx.x;
    const int w = t >> 6, lane = t & 63, quad = lane >> 4, c = lane & 15;
    const int q0 = qb * 64 + w * 16;

    if (t < 192) { biL[t] = gbi[t]; biL[192 + t] = gbh[t]; }
#pragma unroll
    for (int it = 0; it < 6; ++it) {
        int task = it * 256 + t;              // 1536 = 64 k x 24 n-chunks
        int k = task / 24, nc = task - k * 24;
        bfx8 h, l;
        split8(gwi + k * 192 + nc * 8, h, l);
#pragma unroll
        for (int j = 0; j < 8; ++j) { Wh[nc * 8 + j][k] = h[j]; Wl[nc * 8 + j][k] = l[j]; }
    }
    __syncthreads();

    const v4f zero4 = {0.f, 0.f, 0.f, 0.f};
    v4f gi[12], gh[12];
#pragma unroll
    for (int nt = 0; nt < 12; ++nt) gi[nt] = zero4;
#pragma unroll
    for (int ks = 0; ks < 2; ++ks) {
        bfx8 ah, al;
        split8(Xg + (long)(n * 512 + q0 + c) * 512 + hd * 64 + ks * 32 + quad * 8, ah, al);
#pragma unroll
        for (int nt = 0; nt < 12; ++nt) {
            bfx8 bh = *(const bfx8*)(&Wh[nt * 16 + c][ks * 32 + quad * 8]);
            bfx8 bl = *(const bfx8*)(&Wl[nt * 16 + c][ks * 32 + quad * 8]);
            gi[nt] = mfma16(ah, bh, gi[nt]);
            gi[nt] = mfma16(ah, bl, gi[nt]);
            gi[nt] = mfma16(al, bh, gi[nt]);
        }
    }
    __syncthreads();
#pragma unroll
    for (int it = 0; it < 6; ++it) {
        int task = it * 256 + t;
        int k = task / 24, nc = task - k * 24;
        bfx8 h, l;
        split8(gwh + k * 192 + nc * 8, h, l);
#pragma unroll
        for (int j = 0; j < 8; ++j) { Wh[nc * 8 + j][k] = h[j]; Wl[nc * 8 + j][k] = l[j]; }
    }
    __syncthreads();
#pragma unroll
    for (int nt = 0; nt < 12; ++nt) gh[nt] = zero4;
#pragma unroll
    for (int ks = 0; ks < 2; ++ks) {
        bfx8 ah, al;
        split8(hp + (long)(nh * 512 + q0 + c) * 64 + ks * 32 + quad * 8, ah, al);
#pragma unroll
        for (int nt = 0; nt < 12; ++nt) {
            bfx8 bh = *(const bfx8*)(&Wh[nt * 16 + c][ks * 32 + quad * 8]);
            bfx8 bl = *(const bfx8*)(&Wl[nt * 16 + c][ks * 32 + quad * 8]);
            gh[nt] = mfma16(ah, bh, gh[nt]);
            gh[nt] = mfma16(ah, bl, gh[nt]);
            gh[nt] = mfma16(al, bh, gh[nt]);
        }
    }

    // GRU elementwise: rows q0+quad*4+i, d = t4*16+c
    float st[4][4];
#pragma unroll
    for (int t4 = 0; t4 < 4; ++t4) {
        float bir = biL[t4 * 16 + c];
        float biz = biL[64 + t4 * 16 + c];
        float bin = biL[128 + t4 * 16 + c];
        float bhr = biL[192 + t4 * 16 + c];
        float bhz = biL[256 + t4 * 16 + c];
        float bhn = biL[320 + t4 * 16 + c];
#pragma unroll
        for (int i = 0; i < 4; ++i) {
            int row = q0 + quad * 4 + i;
            float r = sigm(gi[t4][i] + bir + gh[t4][i] + bhr);
            float z = sigm(gi[t4 + 4][i] + biz + gh[t4 + 4][i] + bhz);
            float nn_ = tanhf(gi[t4 + 8][i] + bin + r * (gh[t4 + 8][i] + bhn));
            float hpv = hp[(long)(nh * 512 + row) * 64 + t4 * 16 + c];
            st[t4][i] = (1.0f - z) * nn_ + z * hpv;
        }
    }

    float ws_[4], wr0[4], wr1[4], wr2[4];
#pragma unroll
    for (int t4 = 0; t4 < 4; ++t4) {
        int d = t4 * 16 + c;
        ws_[t4] = Wsigma[hd * 64 + d];
        wr0[t4] = Wrho[(hd * 64 + d) * 3 + 0];
        wr1[t4] = Wrho[(hd * 64 + d) * 3 + 1];
        wr2[t4] = Wrho[(hd * 64 + d) * 3 + 2];
    }
#pragma unroll
    for (int i = 0; i < 4; ++i) {
        float s0 = 0.f, s1 = 0.f, s2 = 0.f, s3 = 0.f;
#pragma unroll
        for (int t4 = 0; t4 < 4; ++t4) {
            float sv = st[t4][i];
            s0 += sv * ws_[t4];
            s1 += sv * wr0[t4];
            s2 += sv * wr1[t4];
            s3 += sv * wr2[t4];
        }
#pragma unroll
        for (int o = 1; o < 16; o <<= 1) {
            s0 += __shfl_xor(s0, o);
            s1 += __shfl_xor(s1, o);
            s2 += __shfl_xor(s2, o);
            s3 += __shfl_xor(s3, o);
        }
        if (c == 0) {
            int row = q0 + quad * 4 + i;
            int idx = nh * 512 + row, rq = n * 512 + row;
            float L = lenv[rq], sp = stepv[rq];
            float sg = (fmaxf(s0, 0.f) + 0.27f) / L;
            float fl = floorf(s1);
            float steps = fl + sigm(10.0f * (fabsf(s1 - fl) - 0.5f));
            float ag = sigm(s2), bg = sigm(s3);
            float mu_ = steps * sp + ag * pa[idx] + bg;
            float mu = fmaxf(0.01f * mu_, fminf(mu_, 1.0f + 0.01f * mu_));
            muv[idx] = mu;
            sigv[idx] = sg;
        }
    }
}

// ---------------------------------------------------------------------------
// Fused attention: per block (n,hd,16-q tile). QK^T (bf16 MFMA) -> f32 dual
// softmax/gaussian + mix -> Plds (C->A layout) -> PV (bf16 MFMA) -> att.
// ---------------------------------------------------------------------------
__global__ __launch_bounds__(256) void attn_fused_kernel(
    const bf16* __restrict__ Qh, const bf16* __restrict__ Kh,
    const bf16* __restrict__ Vh, const int* __restrict__ mask,
    const float* __restrict__ vpos, const float* __restrict__ mixv,
    const float* __restrict__ stepv, const float* __restrict__ muv,
    const float* __restrict__ sigv, bf16* __restrict__ att) {
    __shared__ bf16 KVs[256][72];
    __shared__ bf16 Qs[16][72];
    __shared__ bf16 Plds[16][520];
    __shared__ float vps[512];
    __shared__ float rmax[4][16], rsum[4][16], rgsum[4][16];
    __shared__ float rowmu[16], rowsig[16], rowstep[16], rowmix[16];

    const int b = blockIdx.x;
    const int qt = b & 31, nh = b >> 5, hd = nh & 7, n = nh >> 3;
    const int t = threadIdx.x;

    if (t < 16) {
        int q = qt * 16 + t;
        int idx = nh * 512 + q, rq = n * 512 + q;
        rowmu[t] = muv[idx];
        rowsig[t] = sigv[idx];
        rowstep[t] = stepv[rq];
        rowmix[t] = mixv[rq];
    }
    vps[t] = vpos[t];
    vps[256 + t] = vpos[256 + t];
    if (t < 128) {
        int r = t >> 3, ch = t & 7;
        bfx8 v = *(const bfx8*)(Qh + (long)(n * 512 + qt * 16 + r) * 512 + hd * 64 + ch * 8);
        *(bfx8*)(&Qs[r][ch * 8]) = v;
    }
    __syncthreads();

    const int wave = t >> 6, lane = t & 63;
    const int quad = lane >> 4, c = lane & 15;

    bfx8 afr0 = *(const bfx8*)(&Qs[c][quad * 8]);
    bfx8 afr1 = *(const bfx8*)(&Qs[c][32 + quad * 8]);

    const v4f zero4 = {0.f, 0.f, 0.f, 0.f};
    v4f acc[8];
#pragma unroll
    for (int i = 0; i < 8; ++i) acc[i] = zero4;

#pragma unroll
    for (int ph = 0; ph < 2; ++ph) {
#pragma unroll
        for (int i2 = 0; i2 < 8; ++i2) {
            int idx2 = i2 * 256 + t;
            int r = idx2 >> 3, ch = idx2 & 7;
            bfx8 v = *(const bfx8*)(Kh + (long)(n * 512 + ph * 256 + r) * 512 + hd * 64 + ch * 8);
            *(bfx8*)(&KVs[r][ch * 8]) = v;
        }
        __syncthreads();
#pragma unroll
        for (int tt = 0; tt < 4; ++tt) {
            int t8 = ph * 4 + tt;
            int kr = wave * 64 + tt * 16 + c;
            bfx8 b0 = *(const bfx8*)(&KVs[kr][quad * 8]);
            bfx8 b1 = *(const bfx8*)(&KVs[kr][32 + quad * 8]);
            acc[t8] = mfma16(afr0, b0, acc[t8]);
            acc[t8] = mfma16(afr1, b1, acc[t8]);
        }
        __syncthreads();
    }

#pragma unroll
    for (int t8 = 0; t8 < 8; ++t8) acc[t8] = acc[t8] * 0.125f;  // * D^-0.5

    int mbits = 0;
#pragma unroll
    for (int t8 = 0; t8 < 8; ++t8) {
        int k = ((t8 >> 2) * 256) + wave * 64 + ((t8 & 3) * 16) + c;
#pragma unroll
        for (int i = 0; i < 4; ++i) {
            int qg = qt * 16 + quad * 4 + i;
            if (mask[(long)(n * 512 + qg) * 512 + k]) mbits |= (1 << (t8 * 4 + i));
        }
    }

    const int qloc = quad * 4;
#pragma unroll
    for (int i = 0; i < 4; ++i) {
        float mx = -3.0e38f;
#pragma unroll
        for (int t8 = 0; t8 < 8; ++t8)
            if ((mbits >> (t8 * 4 + i)) & 1) mx = fmaxf(mx, acc[t8][i]);
        mx = fmaxf(mx, __shfl_xor(mx, 1));
        mx = fmaxf(mx, __shfl_xor(mx, 2));
        mx = fmaxf(mx, __shfl_xor(mx, 4));
        mx = fmaxf(mx, __shfl_xor(mx, 8));
        if (c == 0) rmax[wave][qloc + i] = mx;
    }
    __syncthreads();

    float gmx[4];
#pragma unroll
    for (int i = 0; i < 4; ++i)
        gmx[i] = fmaxf(fmaxf(rmax[0][qloc + i], rmax[1][qloc + i]),
                       fmaxf(rmax[2][qloc + i], rmax[3][qloc + i]));

    float psum[4] = {0.f, 0.f, 0.f, 0.f};
    float gsum[4] = {0.f, 0.f, 0.f, 0.f};
#pragma unroll
    for (int t8 = 0; t8 < 8; ++t8) {
        int k = ((t8 >> 2) * 256) + wave * 64 + ((t8 & 3) * 16) + c;
        float vp = vps[k];
#pragma unroll
        for (int i = 0; i < 4; ++i) {
            int on = (mbits >> (t8 * 4 + i)) & 1;
            float pv = on ? expf(fmaxf(acc[t8][i] - gmx[i], -87.f)) : 0.f;
            psum[i] += pv;
            float d = vp * rowstep[qloc + i] - rowmu[qloc + i];
            float sg = rowsig[qloc + i];
            float gv = on ? expf(fmaxf(-(d * d) / (2.0f * sg * sg), -87.f)) : 0.f;
            gsum[i] += gv;
        }
    }
#pragma unroll
    for (int i = 0; i < 4; ++i) {
#pragma unroll
        for (int o = 1; o < 16; o <<= 1) {
            psum[i] += __shfl_xor(psum[i], o);
            gsum[i] += __shfl_xor(gsum[i], o);
        }
        if (c == 0) {
            rsum[wave][qloc + i] = psum[i];
            rgsum[wave][qloc + i] = gsum[i];
        }
    }
    __syncthreads();

    float Sp[4], SgD[4];
#pragma unroll
    for (int i = 0; i < 4; ++i) {
        Sp[i] = rsum[0][qloc + i] + rsum[1][qloc + i] + rsum[2][qloc + i] + rsum[3][qloc + i];
        SgD[i] = rgsum[0][qloc + i] + rgsum[1][qloc + i] + rgsum[2][qloc + i] +
                 rgsum[3][qloc + i] + 512.0f * 1e-20f;
    }

#pragma unroll
    for (int t8 = 0; t8 < 8; ++t8) {
        int k = ((t8 >> 2) * 256) + wave * 64 + ((t8 & 3) * 16) + c;
        float vp = vps[k];
#pragma unroll
        for (int i = 0; i < 4; ++i) {
            int on = (mbits >> (t8 * 4 + i)) & 1;
            float pv = on ? expf(fmaxf(acc[t8][i] - gmx[i], -87.f)) : 0.f;
            float d = vp * rowstep[qloc + i] - rowmu[qloc + i];
            float sg = rowsig[qloc + i];
            float gv = on ? expf(fmaxf(-(d * d) / (2.0f * sg * sg), -87.f)) : 0.f;
            float m_ = rowmix[qloc + i];
            float ov = m_ * gv / SgD[i] + (1.0f - m_) * pv / Sp[i];
            Plds[quad * 4 + i][k] = (bf16)ov;
        }
    }
    __syncthreads();

    bf16 (*Vs)[264] = (bf16(*)[264])(&KVs[0][0]);
    v4f accO = zero4;
#pragma unroll
    for (int ph = 0; ph < 2; ++ph) {
#pragma unroll
        for (int it = 0; it < 8; ++it) {
            int task = it * 256 + t;
            int r = task >> 3, ch = task & 7;
            bfx8 v = *(const bfx8*)(Vh + (long)(n * 512 + ph * 256 + r) * 512 + hd * 64 + ch * 8);
#pragma unroll
            for (int j = 0; j < 8; ++j) Vs[ch * 8 + j][r] = v[j];
        }
        __syncthreads();
#pragma unroll
        for (int ks = 0; ks < 8; ++ks) {
            bfx8 af = *(const bfx8*)(&Plds[c][ph * 256 + ks * 32 + quad * 8]);
            bfx8 bf_ = *(const bfx8*)(&Vs[wave * 16 + c][ks * 32 + quad * 8]);
            accO = mfma16(af, bf_, accO);
        }
        __syncthreads();
    }

#pragma unroll
    for (int i = 0; i < 4; ++i) {
        att[(long)(n * 512 + qt * 16 + quad * 4 + i) * 512 + hd * 64 + wave * 16 + c] =
            (bf16)accO[i];
    }
}

// ---------------------------------------------------------------------------
extern "C" void kernel_launch(void* const* d_in, const int* in_sizes, int n_in,
                              void* d_out, int out_size, void* d_ws, size_t ws_size,
                              hipStream_t stream) {
    (void)in_sizes; (void)n_in; (void)out_size; (void)ws_size;

    const float* Q = (const float*)d_in[0];
    const float* K = (const float*)d_in[1];
    const float* V = (const float*)d_in[2];
    const float* past_state = (const float*)d_in[3];
    const float* past_att = (const float*)d_in[4];
    const float* vpos = (const float*)d_in[5];
    const int* mask = (const int*)d_in[6];
    const float* Wq = (const float*)d_in[7];
    const float* Wk = (const float*)d_in[8];
    const float* Wv = (const float*)d_in[9];
    const float* Wpos = (const float*)d_in[10];
    const float* bpos = (const float*)d_in[11];
    const float* Wsigma = (const float*)d_in[12];
    const float* Wrho = (const float*)d_in[13];
    const float* mix_w = (const float*)d_in[14];
    const float* mix_b = (const float*)d_in[15];
    const float* gwi = (const float*)d_in[16];
    const float* gwh = (const float*)d_in[17];
    const float* gbi = (const float*)d_in[18];
    const float* gbh = (const float*)d_in[19];
    const float* Wc = (const float*)d_in[20];
    float* out = (float*)d_out;

    // ---- workspace layout (~70 MB) ----
    char* p = (char*)d_ws;
    const size_t SZB = 8192UL * 512 * 2;   // bf16 [8192,512] = 8 MiB
    const size_t SZW = 512UL * 512 * 2;    // bf16 [512,512]
    bf16* Qc = (bf16*)p;                   p += SZB;
    bf16* Kc = (bf16*)p;                   p += SZB;
    bf16* Vc = (bf16*)p;                   p += SZB;
    bf16* Wqc = (bf16*)p;                  p += SZW;
    bf16* Wkc = (bf16*)p;                  p += SZW;
    bf16* Wvc = (bf16*)p;                  p += SZW;
    bf16* Wcc = (bf16*)p;                  p += SZW;
    float* Xg = (float*)p;                 // f32 [8192,512] = 16 MiB
    bf16* att = (bf16*)p;                  // alias: Xg dead after gru_fused
    p += 8192UL * 512 * 4;
    bf16* Qh = (bf16*)p;                   p += SZB;
    bf16* Kh = (bf16*)p;                   p += SZB;
    bf16* Vh = (bf16*)p;                   p += SZB;
    float* mixv = (float*)p;               p += 32768;
    float* stepv = (float*)p;              p += 32768;
    float* lenv = (float*)p;               p += 32768;
    float* muv = (float*)p;                p += 262144;
    float* sigv = (float*)p;               p += 262144;

    // ---- converter args ----
    ConvArgs ca;
    const float* csrc[NCV] = {Q, K, V, Wq, Wk, Wv, Wc};
    bf16* cdst[NCV] = {Qc, Kc, Vc, Wqc, Wkc, Wvc, Wcc};
    const long cn[NCV] = {4194304, 4194304, 4194304, 262144, 262144, 262144, 262144};
    int pref = 0;
    for (int i = 0; i < NCV; ++i) {
        ca.src[i] = csrc[i];
        ca.dst[i] = cdst[i];
        ca.n[i] = cn[i];
        ca.pref[i] = pref;
        pref += (int)((cn[i] + 2047) / 2048);
    }
    ca.pref[NCV] = pref;

    dim3 blk(256);
    dim3 gProj(128, 8, 1);

    convert_kernel<<<dim3(pref), blk, 0, stream>>>(ca);

    gemm_nn<bf16><<<gProj, blk, 0, stream>>>(Qc, Wqc, Qh, 512, 512, 512, 512);
    gemm_nn<bf16><<<gProj, blk, 0, stream>>>(Kc, Wkc, Kh, 512, 512, 512, 512);
    gemm_nn<bf16><<<gProj, blk, 0, stream>>>(Vc, Wvc, Vh, 512, 512, 512, 512);
    gemm_split_relu<<<gProj, blk, 0, stream>>>(Q, Wpos, bpos, Xg, 512, 512, 512, 512);

    mix_len_kernel<<<dim3(2048), blk, 0, stream>>>(Q, mask, mix_w, mix_b, mixv, stepv, lenv);

    gru_fused_kernel<<<dim3(1024), blk, 0, stream>>>(
        Xg, past_state, gwi, gwh, gbi, gbh, past_att, Wsigma, Wrho,
        lenv, stepv, muv, sigv);

    attn_fused_kernel<<<dim3(4096), blk, 0, stream>>>(
        Qh, Kh, Vh, mask, vpos, mixv, stepv, muv, sigv, att);

    gemm_nn<float><<<gProj, blk, 0, stream>>>(att, Wcc, out, 512, 512, 512, 512);
}

// Round 7
// 385.206 us; speedup vs baseline: 1.6309x; 1.6309x over previous
//
#include <hip/hip_runtime.h>

// ---------------------------------------------------------------------------
// Multiheaded_GRUMix_Attention on MI355X (gfx950). Inputs f32, output f32.
//
// R7: r6's structure (pre-transposed weights, VhT, bitmask, packed pv/gv)
// + restored f32-grade Xg path (r6's bf16 Xg caused absmax 0.0566: mu error
// ~0.2 sigma through the near-delta location attention). Xg now computed by
// a split-bf16 GEMM (A split in-kernel, B = WposT hi/lo planes, 3 MFMAs) and
// stored as hi+lo bf16 pair; GRU consumes the pair with 3 MFMAs.
// ---------------------------------------------------------------------------

typedef __bf16 bf16;
typedef __bf16 bfx8 __attribute__((ext_vector_type(8)));
typedef float v4f __attribute__((ext_vector_type(4)));

__device__ inline float sigm(float x) { return 1.0f / (1.0f + expf(-x)); }

__device__ inline v4f mfma16(bfx8 a, bfx8 b, v4f c) {
    return __builtin_amdgcn_mfma_f32_16x16x32_bf16(a, b, c, 0, 0, 0);
}

__device__ inline void split8(const float* __restrict__ p, bfx8& hi, bfx8& lo) {
    float4 x = *(const float4*)p;
    float4 y = *(const float4*)(p + 4);
    float v[8] = {x.x, x.y, x.z, x.w, y.x, y.y, y.z, y.w};
#pragma unroll
    for (int j = 0; j < 8; ++j) {
        bf16 h = (bf16)v[j];
        hi[j] = h;
        lo[j] = (bf16)(v[j] - (float)h);
    }
}

__device__ inline unsigned short bfbits(float v) {
    bf16 h = (bf16)v;
    return __builtin_bit_cast(unsigned short, h);
}
__device__ inline float bffrom(unsigned short u) {
    return (float)__builtin_bit_cast(bf16, u);
}

// ---------------------------------------------------------------------------
// Prep 1: plain f32->bf16 convert of Q,K,V.
// ---------------------------------------------------------------------------
__global__ __launch_bounds__(256) void conv_qkv_kernel(
    const float* __restrict__ s0, const float* __restrict__ s1, const float* __restrict__ s2,
    bf16* __restrict__ d0, bf16* __restrict__ d1, bf16* __restrict__ d2) {
    int tb = blockIdx.x >> 11;
    const float* src = tb == 0 ? s0 : (tb == 1 ? s1 : s2);
    bf16* dst = tb == 0 ? d0 : (tb == 1 ? d1 : d2);
    long i0 = (long)(blockIdx.x & 2047) * 2048 + threadIdx.x * 8;
    float4 x = *(const float4*)(src + i0);
    float4 y = *(const float4*)(src + i0 + 4);
    bfx8 o;
    o[0] = (bf16)x.x; o[1] = (bf16)x.y; o[2] = (bf16)x.z; o[3] = (bf16)x.w;
    o[4] = (bf16)y.x; o[5] = (bf16)y.y; o[6] = (bf16)y.z; o[7] = (bf16)y.w;
    *(bfx8*)(dst + i0) = o;
}

// ---------------------------------------------------------------------------
// Prep 2: transpose-convert weights [512][512] f32 -> bf16 W^T[col][k];
// optional lo plane (W^T_lo) for split-precision consumers (Wpos).
// ---------------------------------------------------------------------------
struct TW { const float* src[5]; bf16* dst[5]; bf16* dstlo[5]; };

__global__ __launch_bounds__(256) void trans_w_kernel(TW a) {
    __shared__ float tile[64][68];
    const float* src = a.src[blockIdx.y];
    bf16* dst = a.dst[blockIdx.y];
    bf16* dlo = a.dstlo[blockIdx.y];
    const int rbase = (blockIdx.x >> 3) * 64, cbase = (blockIdx.x & 7) * 64;
    const int t = threadIdx.x;
    const int r = t >> 2, cc = (t & 3) * 16;
    {
        const float* p = src + (long)(rbase + r) * 512 + cbase + cc;
        float4 x0 = *(const float4*)p, x1 = *(const float4*)(p + 4);
        float4 x2 = *(const float4*)(p + 8), x3 = *(const float4*)(p + 12);
        *(float4*)(&tile[r][cc]) = x0;
        *(float4*)(&tile[r][cc + 4]) = x1;
        *(float4*)(&tile[r][cc + 8]) = x2;
        *(float4*)(&tile[r][cc + 12]) = x3;
    }
    __syncthreads();
    {
        bfx8 h0, h1, l0, l1;
#pragma unroll
        for (int j = 0; j < 8; ++j) {
            float v0 = tile[cc + j][r];
            float v1 = tile[cc + 8 + j][r];
            bf16 a0 = (bf16)v0, a1 = (bf16)v1;
            h0[j] = a0; l0[j] = (bf16)(v0 - (float)a0);
            h1[j] = a1; l1[j] = (bf16)(v1 - (float)a1);
        }
        bf16* p = dst + (long)(cbase + r) * 512 + rbase + cc;
        *(bfx8*)p = h0;
        *(bfx8*)(p + 8) = h1;
        if (dlo) {
            bf16* pl = dlo + (long)(cbase + r) * 512 + rbase + cc;
            *(bfx8*)pl = l0;
            *(bfx8*)(pl + 8) = l1;
        }
    }
}

// ---------------------------------------------------------------------------
// Prep 3: GRU weights [64][192] f32 -> split-transposed bf16 [192][64] hi/lo.
// ---------------------------------------------------------------------------
__global__ void gru_prep_kernel(const float* __restrict__ gwi, const float* __restrict__ gwh,
                                bf16* ih, bf16* il, bf16* hh, bf16* hl) {
    const float* src = blockIdx.x ? gwh : gwi;
    bf16* dh = blockIdx.x ? hh : ih;
    bf16* dl = blockIdx.x ? hl : il;
    int n = threadIdx.x;  // 0..191
    for (int k = 0; k < 64; ++k) {
        float v = src[k * 192 + n];
        bf16 h = (bf16)v;
        dh[n * 64 + k] = h;
        dl[n * 64 + k] = (bf16)(v - (float)h);
    }
}

// ---------------------------------------------------------------------------
// bf16 MFMA GEMM with PRE-TRANSPOSED B: C[M,N] = A[M,K] @ BT[N,K]^T.
// BM=BN=64, BK=32; 4 waves x (2x2). All LDS staging vector b128.
// TRANSC: write C^T per 512-row batch (for VhT) via LDS transpose.
// ---------------------------------------------------------------------------
template <bool TRANSC, typename OutT>
__global__ __launch_bounds__(256) void gemm_bt(
    const bf16* __restrict__ A, const bf16* __restrict__ BT,
    OutT* __restrict__ C) {
    __shared__ bf16 As[64][72];
    __shared__ bf16 Bs[64][72];

    const int mbase = blockIdx.x * 64, nbase = blockIdx.y * 64;
    const int t = threadIdx.x;
    const int wave = t >> 6, lane = t & 63;
    const int quad = lane >> 4, c = lane & 15;
    const int wrow = (wave >> 1) * 32, wcol = (wave & 1) * 32;

    const v4f zero4 = {0.f, 0.f, 0.f, 0.f};
    v4f acc[2][2];
    acc[0][0] = zero4; acc[0][1] = zero4; acc[1][0] = zero4; acc[1][1] = zero4;

    const int sr = t >> 2, sch = t & 3;

    for (int k0 = 0; k0 < 512; k0 += 32) {
        bfx8 va = *(const bfx8*)(A + (long)(mbase + sr) * 512 + k0 + sch * 8);
        bfx8 vb = *(const bfx8*)(BT + (long)(nbase + sr) * 512 + k0 + sch * 8);
        *(bfx8*)(&As[sr][sch * 8]) = va;
        *(bfx8*)(&Bs[sr][sch * 8]) = vb;
        __syncthreads();

        bfx8 a0 = *(const bfx8*)(&As[wrow + c][quad * 8]);
        bfx8 a1 = *(const bfx8*)(&As[wrow + 16 + c][quad * 8]);
        bfx8 b0 = *(const bfx8*)(&Bs[wcol + c][quad * 8]);
        bfx8 b1 = *(const bfx8*)(&Bs[wcol + 16 + c][quad * 8]);
        acc[0][0] = mfma16(a0, b0, acc[0][0]);
        acc[0][1] = mfma16(a0, b1, acc[0][1]);
        acc[1][0] = mfma16(a1, b0, acc[1][0]);
        acc[1][1] = mfma16(a1, b1, acc[1][1]);
        __syncthreads();
    }

    if (TRANSC) {
#pragma unroll
        for (int tm = 0; tm < 2; ++tm)
#pragma unroll
            for (int tn = 0; tn < 2; ++tn)
#pragma unroll
                for (int i = 0; i < 4; ++i) {
                    int rl = wrow + tm * 16 + quad * 4 + i;
                    int cl = wcol + tn * 16 + c;
                    As[cl][rl] = (bf16)acc[tm][tn][i];
                }
        __syncthreads();
        OutT* CT = C + ((long)(mbase >> 9)) * 262144 + (long)nbase * 512 + (mbase & 511);
        const int rr = t >> 2, kc = (t & 3) * 16;
        bfx8 o0, o1;
#pragma unroll
        for (int j = 0; j < 8; ++j) { o0[j] = As[rr][kc + j]; o1[j] = As[rr][kc + 8 + j]; }
        *(bfx8*)(CT + (long)rr * 512 + kc) = o0;
        *(bfx8*)(CT + (long)rr * 512 + kc + 8) = o1;
    } else {
#pragma unroll
        for (int tm = 0; tm < 2; ++tm)
#pragma unroll
            for (int tn = 0; tn < 2; ++tn)
#pragma unroll
                for (int i = 0; i < 4; ++i) {
                    int row = mbase + wrow + tm * 16 + quad * 4 + i;
                    int col = nbase + wcol + tn * 16 + c;
                    C[(long)row * 512 + col] = (OutT)acc[tm][tn][i];
                }
    }
}

// ---------------------------------------------------------------------------
// Split-bf16 GEMM for Xg: C = relu(A@B+bias), A f32 (split in-kernel),
// B = BT hi/lo planes. Output stored as hi+lo bf16 pair (f32-grade value).
// ---------------------------------------------------------------------------
__global__ __launch_bounds__(256) void gemm_split_hl(
    const float* __restrict__ A, const bf16* __restrict__ BTh,
    const bf16* __restrict__ BTl, const float* __restrict__ bias,
    bf16* __restrict__ Ch, bf16* __restrict__ Cl) {
    __shared__ bf16 Ah[64][72], Al[64][72];
    __shared__ bf16 Bh[64][72], Bl[64][72];

    const int mbase = blockIdx.x * 64, nbase = blockIdx.y * 64;
    const int t = threadIdx.x;
    const int wave = t >> 6, lane = t & 63;
    const int quad = lane >> 4, c = lane & 15;
    const int wrow = (wave >> 1) * 32, wcol = (wave & 1) * 32;

    const v4f zero4 = {0.f, 0.f, 0.f, 0.f};
    v4f acc[2][2];
    acc[0][0] = zero4; acc[0][1] = zero4; acc[1][0] = zero4; acc[1][1] = zero4;

    const int sr = t >> 2, sch = t & 3;

    for (int k0 = 0; k0 < 512; k0 += 32) {
        bfx8 h, l;
        split8(A + (long)(mbase + sr) * 512 + k0 + sch * 8, h, l);
        *(bfx8*)(&Ah[sr][sch * 8]) = h;
        *(bfx8*)(&Al[sr][sch * 8]) = l;
        *(bfx8*)(&Bh[sr][sch * 8]) = *(const bfx8*)(BTh + (long)(nbase + sr) * 512 + k0 + sch * 8);
        *(bfx8*)(&Bl[sr][sch * 8]) = *(const bfx8*)(BTl + (long)(nbase + sr) * 512 + k0 + sch * 8);
        __syncthreads();

        bfx8 ah0 = *(const bfx8*)(&Ah[wrow + c][quad * 8]);
        bfx8 ah1 = *(const bfx8*)(&Ah[wrow + 16 + c][quad * 8]);
        bfx8 al0 = *(const bfx8*)(&Al[wrow + c][quad * 8]);
        bfx8 al1 = *(const bfx8*)(&Al[wrow + 16 + c][quad * 8]);
        bfx8 bh0 = *(const bfx8*)(&Bh[wcol + c][quad * 8]);
        bfx8 bh1 = *(const bfx8*)(&Bh[wcol + 16 + c][quad * 8]);
        bfx8 bl0 = *(const bfx8*)(&Bl[wcol + c][quad * 8]);
        bfx8 bl1 = *(const bfx8*)(&Bl[wcol + 16 + c][quad * 8]);
        acc[0][0] = mfma16(ah0, bh0, acc[0][0]);
        acc[0][0] = mfma16(ah0, bl0, acc[0][0]);
        acc[0][0] = mfma16(al0, bh0, acc[0][0]);
        acc[0][1] = mfma16(ah0, bh1, acc[0][1]);
        acc[0][1] = mfma16(ah0, bl1, acc[0][1]);
        acc[0][1] = mfma16(al0, bh1, acc[0][1]);
        acc[1][0] = mfma16(ah1, bh0, acc[1][0]);
        acc[1][0] = mfma16(ah1, bl0, acc[1][0]);
        acc[1][0] = mfma16(al1, bh0, acc[1][0]);
        acc[1][1] = mfma16(ah1, bh1, acc[1][1]);
        acc[1][1] = mfma16(ah1, bl1, acc[1][1]);
        acc[1][1] = mfma16(al1, bh1, acc[1][1]);
        __syncthreads();
    }

#pragma unroll
    for (int tm = 0; tm < 2; ++tm)
#pragma unroll
        for (int tn = 0; tn < 2; ++tn)
#pragma unroll
            for (int i = 0; i < 4; ++i) {
                int row = mbase + wrow + tm * 16 + quad * 4 + i;
                int col = nbase + wcol + tn * 16 + c;
                float v = fmaxf(acc[tm][tn][i] + bias[col], 0.f);
                bf16 h = (bf16)v;
                Ch[(long)row * 512 + col] = h;
                Cl[(long)row * 512 + col] = (bf16)(v - (float)h);
            }
}

// ---------------------------------------------------------------------------
// mix gate + lengths + packed mask bitmasks: one wave per (n,q) row.
// ---------------------------------------------------------------------------
__global__ __launch_bounds__(256) void mix_len_kernel(
    const float* __restrict__ Q, const int* __restrict__ mask,
    const float* __restrict__ mix_w, const float* __restrict__ mix_b,
    float* __restrict__ mixv, float* __restrict__ stepv, float* __restrict__ lenv,
    unsigned* __restrict__ maskbits) {
    int row = blockIdx.x * 4 + (threadIdx.x >> 6);
    int lane = threadIdx.x & 63;
    float dot = 0.f, ms = 0.f;
    unsigned myw = 0;
#pragma unroll
    for (int j = 0; j < 8; ++j) {
        float qv = Q[(long)row * 512 + j * 64 + lane];
        float wv = mix_w[j * 64 + lane];
        dot += qv * wv;
        int mv = mask[(long)row * 512 + j * 64 + lane];
        unsigned long long b = __ballot(mv != 0);
        ms += (float)__popcll(b);
        if ((lane >> 1) == j) myw = (unsigned)(b >> ((lane & 1) * 32));
    }
#pragma unroll
    for (int o = 32; o > 0; o >>= 1) dot += __shfl_xor(dot, o);
    if (lane < 16) maskbits[(long)row * 16 + lane] = myw;
    if (lane == 0) {
        mixv[row] = sigm(dot + mix_b[0]);
        lenv[row] = ms;
        stepv[row] = 1.0f / fmaxf(1.0f, ms - 1.0f);
    }
}

// ---------------------------------------------------------------------------
// Fused GRU: 64 rows/block of one (n,hd). Split Xg (hi/lo) and split hp;
// pre-split transposed weights; 3 MFMAs per product.
// ---------------------------------------------------------------------------
__global__ __launch_bounds__(256) void gru_fused_kernel(
    const bf16* __restrict__ Xh, const bf16* __restrict__ Xl,
    const float* __restrict__ hp,
    const bf16* __restrict__ wih, const bf16* __restrict__ wil,
    const bf16* __restrict__ whh, const bf16* __restrict__ whl,
    const float* __restrict__ gbi, const float* __restrict__ gbh,
    const float* __restrict__ pa, const float* __restrict__ Wsigma,
    const float* __restrict__ Wrho,
    const float* __restrict__ lenv, const float* __restrict__ stepv,
    float* __restrict__ muv, float* __restrict__ sigv) {
    __shared__ bf16 Wh[192][72], Wl[192][72];
    __shared__ float biL[384];

    const int b = blockIdx.x;
    const int qb = b & 7, nh = b >> 3, hd = nh & 7, n = nh >> 3;
    const int t = threadIdx.x;
    const int w = t >> 6, lane = t & 63, quad = lane >> 4, c = lane & 15;
    const int q0 = qb * 64 + w * 16;

    if (t < 192) { biL[t] = gbi[t]; biL[192 + t] = gbh[t]; }
#pragma unroll
    for (int it = 0; it < 6; ++it) {
        int task = it * 256 + t;
        int r = task >> 3, ch = task & 7;
        *(bfx8*)(&Wh[r][ch * 8]) = *(const bfx8*)(wih + r * 64 + ch * 8);
        *(bfx8*)(&Wl[r][ch * 8]) = *(const bfx8*)(wil + r * 64 + ch * 8);
    }
    __syncthreads();

    const v4f zero4 = {0.f, 0.f, 0.f, 0.f};
    v4f gi[12], gh[12];
#pragma unroll
    for (int nt = 0; nt < 12; ++nt) gi[nt] = zero4;
#pragma unroll
    for (int ks = 0; ks < 2; ++ks) {
        long ao = (long)(n * 512 + q0 + c) * 512 + hd * 64 + ks * 32 + quad * 8;
        bfx8 xh = *(const bfx8*)(Xh + ao);
        bfx8 xl = *(const bfx8*)(Xl + ao);
#pragma unroll
        for (int nt = 0; nt < 12; ++nt) {
            bfx8 bh = *(const bfx8*)(&Wh[nt * 16 + c][ks * 32 + quad * 8]);
            bfx8 bl = *(const bfx8*)(&Wl[nt * 16 + c][ks * 32 + quad * 8]);
            gi[nt] = mfma16(xh, bh, gi[nt]);
            gi[nt] = mfma16(xh, bl, gi[nt]);
            gi[nt] = mfma16(xl, bh, gi[nt]);
        }
    }
    __syncthreads();
#pragma unroll
    for (int it = 0; it < 6; ++it) {
        int task = it * 256 + t;
        int r = task >> 3, ch = task & 7;
        *(bfx8*)(&Wh[r][ch * 8]) = *(const bfx8*)(whh + r * 64 + ch * 8);
        *(bfx8*)(&Wl[r][ch * 8]) = *(const bfx8*)(whl + r * 64 + ch * 8);
    }
    __syncthreads();
#pragma unroll
    for (int nt = 0; nt < 12; ++nt) gh[nt] = zero4;
#pragma unroll
    for (int ks = 0; ks < 2; ++ks) {
        bfx8 ah, al;
        split8(hp + (long)(nh * 512 + q0 + c) * 64 + ks * 32 + quad * 8, ah, al);
#pragma unroll
        for (int nt = 0; nt < 12; ++nt) {
            bfx8 bh = *(const bfx8*)(&Wh[nt * 16 + c][ks * 32 + quad * 8]);
            bfx8 bl = *(const bfx8*)(&Wl[nt * 16 + c][ks * 32 + quad * 8]);
            gh[nt] = mfma16(ah, bh, gh[nt]);
            gh[nt] = mfma16(ah, bl, gh[nt]);
            gh[nt] = mfma16(al, bh, gh[nt]);
        }
    }

    float st[4][4];
#pragma unroll
    for (int t4 = 0; t4 < 4; ++t4) {
        float bir = biL[t4 * 16 + c];
        float biz = biL[64 + t4 * 16 + c];
        float bin = biL[128 + t4 * 16 + c];
        float bhr = biL[192 + t4 * 16 + c];
        float bhz = biL[256 + t4 * 16 + c];
        float bhn = biL[320 + t4 * 16 + c];
#pragma unroll
        for (int i = 0; i < 4; ++i) {
            int row = q0 + quad * 4 + i;
            float r = sigm(gi[t4][i] + bir + gh[t4][i] + bhr);
            float z = sigm(gi[t4 + 4][i] + biz + gh[t4 + 4][i] + bhz);
            float nn_ = tanhf(gi[t4 + 8][i] + bin + r * (gh[t4 + 8][i] + bhn));
            float hpv = hp[(long)(nh * 512 + row) * 64 + t4 * 16 + c];
            st[t4][i] = (1.0f - z) * nn_ + z * hpv;
        }
    }

    float ws_[4], wr0[4], wr1[4], wr2[4];
#pragma unroll
    for (int t4 = 0; t4 < 4; ++t4) {
        int d = t4 * 16 + c;
        ws_[t4] = Wsigma[hd * 64 + d];
        wr0[t4] = Wrho[(hd * 64 + d) * 3 + 0];
        wr1[t4] = Wrho[(hd * 64 + d) * 3 + 1];
        wr2[t4] = Wrho[(hd * 64 + d) * 3 + 2];
    }
#pragma unroll
    for (int i = 0; i < 4; ++i) {
        float s0 = 0.f, s1 = 0.f, s2 = 0.f, s3 = 0.f;
#pragma unroll
        for (int t4 = 0; t4 < 4; ++t4) {
            float sv = st[t4][i];
            s0 += sv * ws_[t4];
            s1 += sv * wr0[t4];
            s2 += sv * wr1[t4];
            s3 += sv * wr2[t4];
        }
#pragma unroll
        for (int o = 1; o < 16; o <<= 1) {
            s0 += __shfl_xor(s0, o);
            s1 += __shfl_xor(s1, o);
            s2 += __shfl_xor(s2, o);
            s3 += __shfl_xor(s3, o);
        }
        if (c == 0) {
            int row = q0 + quad * 4 + i;
            int idx = nh * 512 + row, rq = n * 512 + row;
            float L = lenv[rq], sp = stepv[rq];
            float sg = (fmaxf(s0, 0.f) + 0.27f) / L;
            float fl = floorf(s1);
            float steps = fl + sigm(10.0f * (fabsf(s1 - fl) - 0.5f));
            float ag = sigm(s2), bg = sigm(s3);
            float mu_ = steps * sp + ag * pa[idx] + bg;
            float mu = fmaxf(0.01f * mu_, fminf(mu_, 1.0f + 0.01f * mu_));
            muv[idx] = mu;
            sigv[idx] = sg;
        }
    }
}

// ---------------------------------------------------------------------------
// Fused attention: per block (n,hd,16-q tile); 128-row K/V phases; bitmask
// mask; pv/gv packed in VGPRs; VhT for conflict-free PV staging.
// LDS ~40.4 KB -> 3 blocks/CU.
// ---------------------------------------------------------------------------
__global__ __launch_bounds__(256) void attn_fused_kernel(
    const bf16* __restrict__ Qh, const bf16* __restrict__ Kh,
    const bf16* __restrict__ VhT, const unsigned* __restrict__ maskbits,
    const float* __restrict__ vpos, const float* __restrict__ mixv,
    const float* __restrict__ stepv, const float* __restrict__ muv,
    const float* __restrict__ sigv, bf16* __restrict__ att) {
    __shared__ alignas(16) char KVraw[128 * 72 * 2];  // Ks[128][72] / Vs[64][136]
    __shared__ bf16 Qs[16][72];
    __shared__ bf16 Plds[16][520];
    __shared__ float vps[512];
    __shared__ float rmax[4][16], rsum[4][16], rgsum[4][16];
    __shared__ float rowmu[16], rowsig[16], rowstep[16], rowmix[16];
    bf16 (*Ks)[72] = (bf16(*)[72])KVraw;
    bf16 (*Vs)[136] = (bf16(*)[136])KVraw;

    const int b = blockIdx.x;
    const int qt = b & 31, nh = b >> 5, hd = nh & 7, n = nh >> 3;
    const int t = threadIdx.x;

    if (t < 16) {
        int q = qt * 16 + t;
        int idx = nh * 512 + q, rq = n * 512 + q;
        rowmu[t] = muv[idx];
        rowsig[t] = sigv[idx];
        rowstep[t] = stepv[rq];
        rowmix[t] = mixv[rq];
    }
    vps[t] = vpos[t];
    vps[256 + t] = vpos[256 + t];
    if (t < 128) {
        int r = t >> 3, ch = t & 7;
        bfx8 v = *(const bfx8*)(Qh + (long)(n * 512 + qt * 16 + r) * 512 + hd * 64 + ch * 8);
        *(bfx8*)(&Qs[r][ch * 8]) = v;
    }
    __syncthreads();

    const int wave = t >> 6, lane = t & 63;
    const int quad = lane >> 4, c = lane & 15;
    const int qloc = quad * 4;

    bfx8 afr0 = *(const bfx8*)(&Qs[c][quad * 8]);
    bfx8 afr1 = *(const bfx8*)(&Qs[c][32 + quad * 8]);

    const v4f zero4 = {0.f, 0.f, 0.f, 0.f};
    v4f acc[8];
#pragma unroll
    for (int i = 0; i < 8; ++i) acc[i] = zero4;

#pragma unroll
    for (int ph = 0; ph < 4; ++ph) {
#pragma unroll
        for (int it = 0; it < 4; ++it) {
            int task = it * 256 + t;
            int r = task >> 3, ch = task & 7;
            *(bfx8*)(&Ks[r][ch * 8]) =
                *(const bfx8*)(Kh + (long)(n * 512 + ph * 128 + r) * 512 + hd * 64 + ch * 8);
        }
        __syncthreads();
#pragma unroll
        for (int tt = 0; tt < 2; ++tt) {
            int t8 = ph * 2 + tt;
            int kr = wave * 32 + tt * 16 + c;
            bfx8 b0 = *(const bfx8*)(&Ks[kr][quad * 8]);
            bfx8 b1 = *(const bfx8*)(&Ks[kr][32 + quad * 8]);
            acc[t8] = mfma16(afr0, b0, acc[t8]);
            acc[t8] = mfma16(afr1, b1, acc[t8]);
        }
        __syncthreads();
    }

#pragma unroll
    for (int t8 = 0; t8 < 8; ++t8) acc[t8] = acc[t8] * 0.125f;

    unsigned mw[4][4];
#pragma unroll
    for (int i = 0; i < 4; ++i) {
        const unsigned* mrow = maskbits + (long)(n * 512 + qt * 16 + qloc + i) * 16 + wave;
        mw[i][0] = mrow[0];
        mw[i][1] = mrow[4];
        mw[i][2] = mrow[8];
        mw[i][3] = mrow[12];
    }

#pragma unroll
    for (int i = 0; i < 4; ++i) {
        float mx = -3.0e38f;
#pragma unroll
        for (int t8 = 0; t8 < 8; ++t8)
            if ((mw[i][t8 >> 1] >> ((t8 & 1) * 16 + c)) & 1) mx = fmaxf(mx, acc[t8][i]);
        mx = fmaxf(mx, __shfl_xor(mx, 1));
        mx = fmaxf(mx, __shfl_xor(mx, 2));
        mx = fmaxf(mx, __shfl_xor(mx, 4));
        mx = fmaxf(mx, __shfl_xor(mx, 8));
        if (c == 0) rmax[wave][qloc + i] = mx;
    }
    __syncthreads();

    float gmx[4], inv2s[4];
#pragma unroll
    for (int i = 0; i < 4; ++i) {
        gmx[i] = fmaxf(fmaxf(rmax[0][qloc + i], rmax[1][qloc + i]),
                       fmaxf(rmax[2][qloc + i], rmax[3][qloc + i]));
        float sg = rowsig[qloc + i];
        inv2s[i] = 0.5f / (sg * sg);
    }

    float psum[4] = {0.f, 0.f, 0.f, 0.f};
    float gsum[4] = {0.f, 0.f, 0.f, 0.f};
    unsigned pg[8][4];
#pragma unroll
    for (int t8 = 0; t8 < 8; ++t8) {
        int k = (t8 >> 1) * 128 + wave * 32 + (t8 & 1) * 16 + c;
        float vp = vps[k];
#pragma unroll
        for (int i = 0; i < 4; ++i) {
            int on = (mw[i][t8 >> 1] >> ((t8 & 1) * 16 + c)) & 1;
            float pv = on ? expf(acc[t8][i] - gmx[i]) : 0.f;
            float d = vp * rowstep[qloc + i] - rowmu[qloc + i];
            float gv = on ? expf(-(d * d) * inv2s[i]) : 0.f;
            psum[i] += pv;
            gsum[i] += gv;
            pg[t8][i] = ((unsigned)bfbits(gv) << 16) | (unsigned)bfbits(pv);
        }
    }
#pragma unroll
    for (int i = 0; i < 4; ++i) {
#pragma unroll
        for (int o = 1; o < 16; o <<= 1) {
            psum[i] += __shfl_xor(psum[i], o);
            gsum[i] += __shfl_xor(gsum[i], o);
        }
        if (c == 0) {
            rsum[wave][qloc + i] = psum[i];
            rgsum[wave][qloc + i] = gsum[i];
        }
    }
    __syncthreads();

    float ac[4], bc[4];
#pragma unroll
    for (int i = 0; i < 4; ++i) {
        float Sp = rsum[0][qloc + i] + rsum[1][qloc + i] + rsum[2][qloc + i] + rsum[3][qloc + i];
        float Sg = rgsum[0][qloc + i] + rgsum[1][qloc + i] + rgsum[2][qloc + i] +
                   rgsum[3][qloc + i] + 512.0f * 1e-20f;
        float m_ = rowmix[qloc + i];
        ac[i] = (1.0f - m_) / Sp;
        bc[i] = m_ / Sg;
    }

#pragma unroll
    for (int t8 = 0; t8 < 8; ++t8) {
        int k = (t8 >> 1) * 128 + wave * 32 + (t8 & 1) * 16 + c;
#pragma unroll
        for (int i = 0; i < 4; ++i) {
            float pv = bffrom((unsigned short)(pg[t8][i] & 0xffffu));
            float gv = bffrom((unsigned short)(pg[t8][i] >> 16));
            Plds[qloc + i][k] = (bf16)(pv * ac[i] + gv * bc[i]);
        }
    }
    __syncthreads();

    v4f accO = zero4;
#pragma unroll
    for (int ph = 0; ph < 4; ++ph) {
#pragma unroll
        for (int it = 0; it < 4; ++it) {
            int task = it * 256 + t;
            int v = task >> 4, ch = task & 15;
            *(bfx8*)(&Vs[v][ch * 8]) =
                *(const bfx8*)(VhT + (long)(n * 512 + hd * 64 + v) * 512 + ph * 128 + ch * 8);
        }
        __syncthreads();
#pragma unroll
        for (int ks = 0; ks < 4; ++ks) {
            bfx8 af = *(const bfx8*)(&Plds[c][ph * 128 + ks * 32 + quad * 8]);
            bfx8 bf_ = *(const bfx8*)(&Vs[wave * 16 + c][ks * 32 + quad * 8]);
            accO = mfma16(af, bf_, accO);
        }
        __syncthreads();
    }

#pragma unroll
    for (int i = 0; i < 4; ++i) {
        att[(long)(n * 512 + qt * 16 + quad * 4 + i) * 512 + hd * 64 + wave * 16 + c] =
            (bf16)accO[i];
    }
}

// ---------------------------------------------------------------------------
extern "C" void kernel_launch(void* const* d_in, const int* in_sizes, int n_in,
                              void* d_out, int out_size, void* d_ws, size_t ws_size,
                              hipStream_t stream) {
    (void)in_sizes; (void)n_in; (void)out_size; (void)ws_size;

    const float* Q = (const float*)d_in[0];
    const float* K = (const float*)d_in[1];
    const float* V = (const float*)d_in[2];
    const float* past_state = (const float*)d_in[3];
    const float* past_att = (const float*)d_in[4];
    const float* vpos = (const float*)d_in[5];
    const int* mask = (const int*)d_in[6];
    const float* Wq = (const float*)d_in[7];
    const float* Wk = (const float*)d_in[8];
    const float* Wv = (const float*)d_in[9];
    const float* Wpos = (const float*)d_in[10];
    const float* bpos = (const float*)d_in[11];
    const float* Wsigma = (const float*)d_in[12];
    const float* Wrho = (const float*)d_in[13];
    const float* mix_w = (const float*)d_in[14];
    const float* mix_b = (const float*)d_in[15];
    const float* gwi = (const float*)d_in[16];
    const float* gwh = (const float*)d_in[17];
    const float* gbi = (const float*)d_in[18];
    const float* gbh = (const float*)d_in[19];
    const float* Wc = (const float*)d_in[20];
    float* out = (float*)d_out;

    // ---- workspace ----
    char* p = (char*)d_ws;
    const size_t SZB = 8192UL * 512 * 2;   // 8 MiB
    const size_t SZW = 512UL * 512 * 2;    // 512 KiB
    bf16* Qc = (bf16*)p;    p += SZB;
    bf16* Kc = (bf16*)p;    p += SZB;
    bf16* Vc = (bf16*)p;    p += SZB;
    bf16* WqT = (bf16*)p;   p += SZW;
    bf16* WkT = (bf16*)p;   p += SZW;
    bf16* WvT = (bf16*)p;   p += SZW;
    bf16* WpT = (bf16*)p;   p += SZW;
    bf16* WpTl = (bf16*)p;  p += SZW;
    bf16* WcT = (bf16*)p;   p += SZW;
    bf16* wih = (bf16*)p;   p += 24576;
    bf16* wil = (bf16*)p;   p += 24576;
    bf16* whh = (bf16*)p;   p += 24576;
    bf16* whl = (bf16*)p;   p += 24576;
    bf16* Qh = (bf16*)p;    p += SZB;
    bf16* Kh = (bf16*)p;    p += SZB;
    bf16* VhT = (bf16*)p;   p += SZB;
    bf16* Xh = (bf16*)p;                 // aliased as att after gru
    bf16* att = Xh;         p += SZB;
    bf16* Xl = (bf16*)p;    p += SZB;
    unsigned* maskbits = (unsigned*)p;   p += 8192UL * 16 * 4;
    float* mixv = (float*)p;  p += 32768;
    float* stepv = (float*)p; p += 32768;
    float* lenv = (float*)p;  p += 32768;
    float* muv = (float*)p;   p += 262144;
    float* sigv = (float*)p;  p += 262144;

    dim3 blk(256);
    dim3 gProj(128, 8, 1);

    conv_qkv_kernel<<<dim3(6144), blk, 0, stream>>>(Q, K, V, Qc, Kc, Vc);

    TW tw;
    tw.src[0] = Wq; tw.src[1] = Wk; tw.src[2] = Wv; tw.src[3] = Wpos; tw.src[4] = Wc;
    tw.dst[0] = WqT; tw.dst[1] = WkT; tw.dst[2] = WvT; tw.dst[3] = WpT; tw.dst[4] = WcT;
    tw.dstlo[0] = nullptr; tw.dstlo[1] = nullptr; tw.dstlo[2] = nullptr;
    tw.dstlo[3] = WpTl; tw.dstlo[4] = nullptr;
    trans_w_kernel<<<dim3(64, 5), blk, 0, stream>>>(tw);

    gru_prep_kernel<<<dim3(2), dim3(192), 0, stream>>>(gwi, gwh, wih, wil, whh, whl);

    gemm_bt<false, bf16><<<gProj, blk, 0, stream>>>(Qc, WqT, Qh);
    gemm_bt<false, bf16><<<gProj, blk, 0, stream>>>(Kc, WkT, Kh);
    gemm_bt<true, bf16><<<gProj, blk, 0, stream>>>(Vc, WvT, VhT);
    gemm_split_hl<<<gProj, blk, 0, stream>>>(Q, WpT, WpTl, bpos, Xh, Xl);

    mix_len_kernel<<<dim3(2048), blk, 0, stream>>>(Q, mask, mix_w, mix_b, mixv, stepv, lenv, maskbits);

    gru_fused_kernel<<<dim3(1024), blk, 0, stream>>>(
        Xh, Xl, past_state, wih, wil, whh, whl, gbi, gbh, past_att, Wsigma, Wrho,
        lenv, stepv, muv, sigv);

    attn_fused_kernel<<<dim3(4096), blk, 0, stream>>>(
        Qh, Kh, VhT, maskbits, vpos, mixv, stepv, muv, sigv, att);

    gemm_bt<false, float><<<gProj, blk, 0, stream>>>(att, WcT, out);
}

// Round 8
// 365.887 us; speedup vs baseline: 1.7170x; 1.0528x over previous
//
#include <hip/hip_runtime.h>

// ---------------------------------------------------------------------------
// Multiheaded_GRUMix_Attention on MI355X (gfx950). Inputs f32, output f32.
//
// R8: attn rewrite — per-wave K/V ownership is disjoint, so K/V LDS staging
// and its 16 barriers are deleted; K (row-major) and VhT fragments load
// directly from global (16 B/lane). LDS: Plds + vps + mask + reductions
// ~22.5 KB -> 5+ blocks/CU, 4 barriers total. expf -> __expf (v_exp_f32)
// everywhere (precise OCML expf was ~25 inst each, 64-128/thread).
// 3 projection GEMMs batched into one launch (blockIdx.z).
// ---------------------------------------------------------------------------

typedef __bf16 bf16;
typedef __bf16 bfx8 __attribute__((ext_vector_type(8)));
typedef float v4f __attribute__((ext_vector_type(4)));

__device__ inline float sigm(float x) { return 1.0f / (1.0f + __expf(-x)); }

__device__ inline v4f mfma16(bfx8 a, bfx8 b, v4f c) {
    return __builtin_amdgcn_mfma_f32_16x16x32_bf16(a, b, c, 0, 0, 0);
}

__device__ inline void split8(const float* __restrict__ p, bfx8& hi, bfx8& lo) {
    float4 x = *(const float4*)p;
    float4 y = *(const float4*)(p + 4);
    float v[8] = {x.x, x.y, x.z, x.w, y.x, y.y, y.z, y.w};
#pragma unroll
    for (int j = 0; j < 8; ++j) {
        bf16 h = (bf16)v[j];
        hi[j] = h;
        lo[j] = (bf16)(v[j] - (float)h);
    }
}

// ---------------------------------------------------------------------------
// Prep 1: plain f32->bf16 convert of Q,K,V.
// ---------------------------------------------------------------------------
__global__ __launch_bounds__(256) void conv_qkv_kernel(
    const float* __restrict__ s0, const float* __restrict__ s1, const float* __restrict__ s2,
    bf16* __restrict__ d0, bf16* __restrict__ d1, bf16* __restrict__ d2) {
    int tb = blockIdx.x >> 11;
    const float* src = tb == 0 ? s0 : (tb == 1 ? s1 : s2);
    bf16* dst = tb == 0 ? d0 : (tb == 1 ? d1 : d2);
    long i0 = (long)(blockIdx.x & 2047) * 2048 + threadIdx.x * 8;
    float4 x = *(const float4*)(src + i0);
    float4 y = *(const float4*)(src + i0 + 4);
    bfx8 o;
    o[0] = (bf16)x.x; o[1] = (bf16)x.y; o[2] = (bf16)x.z; o[3] = (bf16)x.w;
    o[4] = (bf16)y.x; o[5] = (bf16)y.y; o[6] = (bf16)y.z; o[7] = (bf16)y.w;
    *(bfx8*)(dst + i0) = o;
}

// ---------------------------------------------------------------------------
// Prep 2: transpose-convert weights [512][512] f32 -> bf16 W^T[col][k];
// optional lo plane for split-precision consumers (Wpos).
// ---------------------------------------------------------------------------
struct TW { const float* src[5]; bf16* dst[5]; bf16* dstlo[5]; };

__global__ __launch_bounds__(256) void trans_w_kernel(TW a) {
    __shared__ float tile[64][68];
    const float* src = a.src[blockIdx.y];
    bf16* dst = a.dst[blockIdx.y];
    bf16* dlo = a.dstlo[blockIdx.y];
    const int rbase = (blockIdx.x >> 3) * 64, cbase = (blockIdx.x & 7) * 64;
    const int t = threadIdx.x;
    const int r = t >> 2, cc = (t & 3) * 16;
    {
        const float* p = src + (long)(rbase + r) * 512 + cbase + cc;
        *(float4*)(&tile[r][cc]) = *(const float4*)p;
        *(float4*)(&tile[r][cc + 4]) = *(const float4*)(p + 4);
        *(float4*)(&tile[r][cc + 8]) = *(const float4*)(p + 8);
        *(float4*)(&tile[r][cc + 12]) = *(const float4*)(p + 12);
    }
    __syncthreads();
    {
        bfx8 h0, h1, l0, l1;
#pragma unroll
        for (int j = 0; j < 8; ++j) {
            float v0 = tile[cc + j][r];
            float v1 = tile[cc + 8 + j][r];
            bf16 a0 = (bf16)v0, a1 = (bf16)v1;
            h0[j] = a0; l0[j] = (bf16)(v0 - (float)a0);
            h1[j] = a1; l1[j] = (bf16)(v1 - (float)a1);
        }
        bf16* p = dst + (long)(cbase + r) * 512 + rbase + cc;
        *(bfx8*)p = h0;
        *(bfx8*)(p + 8) = h1;
        if (dlo) {
            bf16* pl = dlo + (long)(cbase + r) * 512 + rbase + cc;
            *(bfx8*)pl = l0;
            *(bfx8*)(pl + 8) = l1;
        }
    }
}

// ---------------------------------------------------------------------------
// Prep 3: GRU weights [64][192] f32 -> split-transposed bf16 [192][64] hi/lo.
// ---------------------------------------------------------------------------
__global__ void gru_prep_kernel(const float* __restrict__ gwi, const float* __restrict__ gwh,
                                bf16* ih, bf16* il, bf16* hh, bf16* hl) {
    const float* src = blockIdx.x ? gwh : gwi;
    bf16* dh = blockIdx.x ? hh : ih;
    bf16* dl = blockIdx.x ? hl : il;
    int n = threadIdx.x;
    for (int k = 0; k < 64; ++k) {
        float v = src[k * 192 + n];
        bf16 h = (bf16)v;
        dh[n * 64 + k] = h;
        dl[n * 64 + k] = (bf16)(v - (float)h);
    }
}

// ---------------------------------------------------------------------------
// 3 projection GEMMs in one launch: C[M,N] = A[M,K] @ BT[N,K]^T, bf16 out.
// z=2 (V) writes C^T per 512-row batch (VhT).
// ---------------------------------------------------------------------------
struct G3 { const bf16* A[3]; const bf16* BT[3]; bf16* C[3]; };

__global__ __launch_bounds__(256) void gemm_bt3(G3 g) {
    __shared__ bf16 As[64][72];
    __shared__ bf16 Bs[64][72];

    const int z = blockIdx.z;
    const bf16* __restrict__ A = g.A[z];
    const bf16* __restrict__ BT = g.BT[z];
    bf16* __restrict__ C = g.C[z];

    const int mbase = blockIdx.x * 64, nbase = blockIdx.y * 64;
    const int t = threadIdx.x;
    const int wave = t >> 6, lane = t & 63;
    const int quad = lane >> 4, c = lane & 15;
    const int wrow = (wave >> 1) * 32, wcol = (wave & 1) * 32;

    const v4f zero4 = {0.f, 0.f, 0.f, 0.f};
    v4f acc[2][2];
    acc[0][0] = zero4; acc[0][1] = zero4; acc[1][0] = zero4; acc[1][1] = zero4;

    const int sr = t >> 2, sch = t & 3;

    for (int k0 = 0; k0 < 512; k0 += 32) {
        bfx8 va = *(const bfx8*)(A + (long)(mbase + sr) * 512 + k0 + sch * 8);
        bfx8 vb = *(const bfx8*)(BT + (long)(nbase + sr) * 512 + k0 + sch * 8);
        *(bfx8*)(&As[sr][sch * 8]) = va;
        *(bfx8*)(&Bs[sr][sch * 8]) = vb;
        __syncthreads();

        bfx8 a0 = *(const bfx8*)(&As[wrow + c][quad * 8]);
        bfx8 a1 = *(const bfx8*)(&As[wrow + 16 + c][quad * 8]);
        bfx8 b0 = *(const bfx8*)(&Bs[wcol + c][quad * 8]);
        bfx8 b1 = *(const bfx8*)(&Bs[wcol + 16 + c][quad * 8]);
        acc[0][0] = mfma16(a0, b0, acc[0][0]);
        acc[0][1] = mfma16(a0, b1, acc[0][1]);
        acc[1][0] = mfma16(a1, b0, acc[1][0]);
        acc[1][1] = mfma16(a1, b1, acc[1][1]);
        __syncthreads();
    }

    if (z == 2) {
#pragma unroll
        for (int tm = 0; tm < 2; ++tm)
#pragma unroll
            for (int tn = 0; tn < 2; ++tn)
#pragma unroll
                for (int i = 0; i < 4; ++i) {
                    int rl = wrow + tm * 16 + quad * 4 + i;
                    int cl = wcol + tn * 16 + c;
                    As[cl][rl] = (bf16)acc[tm][tn][i];
                }
        __syncthreads();
        bf16* CT = C + ((long)(mbase >> 9)) * 262144 + (long)nbase * 512 + (mbase & 511);
        const int rr = t >> 2, kc = (t & 3) * 16;
        bfx8 o0, o1;
#pragma unroll
        for (int j = 0; j < 8; ++j) { o0[j] = As[rr][kc + j]; o1[j] = As[rr][kc + 8 + j]; }
        *(bfx8*)(CT + (long)rr * 512 + kc) = o0;
        *(bfx8*)(CT + (long)rr * 512 + kc + 8) = o1;
    } else {
#pragma unroll
        for (int tm = 0; tm < 2; ++tm)
#pragma unroll
            for (int tn = 0; tn < 2; ++tn)
#pragma unroll
                for (int i = 0; i < 4; ++i) {
                    int row = mbase + wrow + tm * 16 + quad * 4 + i;
                    int col = nbase + wcol + tn * 16 + c;
                    C[(long)row * 512 + col] = (bf16)acc[tm][tn][i];
                }
    }
}

// ---------------------------------------------------------------------------
// Out GEMM: C[M,N] = A[M,K] @ BT[N,K]^T, f32 out.
// ---------------------------------------------------------------------------
__global__ __launch_bounds__(256) void gemm_out(
    const bf16* __restrict__ A, const bf16* __restrict__ BT, float* __restrict__ C) {
    __shared__ bf16 As[64][72];
    __shared__ bf16 Bs[64][72];

    const int mbase = blockIdx.x * 64, nbase = blockIdx.y * 64;
    const int t = threadIdx.x;
    const int wave = t >> 6, lane = t & 63;
    const int quad = lane >> 4, c = lane & 15;
    const int wrow = (wave >> 1) * 32, wcol = (wave & 1) * 32;

    const v4f zero4 = {0.f, 0.f, 0.f, 0.f};
    v4f acc[2][2];
    acc[0][0] = zero4; acc[0][1] = zero4; acc[1][0] = zero4; acc[1][1] = zero4;

    const int sr = t >> 2, sch = t & 3;

    for (int k0 = 0; k0 < 512; k0 += 32) {
        bfx8 va = *(const bfx8*)(A + (long)(mbase + sr) * 512 + k0 + sch * 8);
        bfx8 vb = *(const bfx8*)(BT + (long)(nbase + sr) * 512 + k0 + sch * 8);
        *(bfx8*)(&As[sr][sch * 8]) = va;
        *(bfx8*)(&Bs[sr][sch * 8]) = vb;
        __syncthreads();

        bfx8 a0 = *(const bfx8*)(&As[wrow + c][quad * 8]);
        bfx8 a1 = *(const bfx8*)(&As[wrow + 16 + c][quad * 8]);
        bfx8 b0 = *(const bfx8*)(&Bs[wcol + c][quad * 8]);
        bfx8 b1 = *(const bfx8*)(&Bs[wcol + 16 + c][quad * 8]);
        acc[0][0] = mfma16(a0, b0, acc[0][0]);
        acc[0][1] = mfma16(a0, b1, acc[0][1]);
        acc[1][0] = mfma16(a1, b0, acc[1][0]);
        acc[1][1] = mfma16(a1, b1, acc[1][1]);
        __syncthreads();
    }

#pragma unroll
    for (int tm = 0; tm < 2; ++tm)
#pragma unroll
        for (int tn = 0; tn < 2; ++tn)
#pragma unroll
            for (int i = 0; i < 4; ++i) {
                int row = mbase + wrow + tm * 16 + quad * 4 + i;
                int col = nbase + wcol + tn * 16 + c;
                C[(long)row * 512 + col] = acc[tm][tn][i];
            }
}

// ---------------------------------------------------------------------------
// Split-bf16 GEMM for Xg: C = relu(A@B+bias), A f32 (split in-kernel),
// B = BT hi/lo planes. Output stored as hi+lo bf16 pair.
// ---------------------------------------------------------------------------
__global__ __launch_bounds__(256) void gemm_split_hl(
    const float* __restrict__ A, const bf16* __restrict__ BTh,
    const bf16* __restrict__ BTl, const float* __restrict__ bias,
    bf16* __restrict__ Ch, bf16* __restrict__ Cl) {
    __shared__ bf16 Ah[64][72], Al[64][72];
    __shared__ bf16 Bh[64][72], Bl[64][72];

    const int mbase = blockIdx.x * 64, nbase = blockIdx.y * 64;
    const int t = threadIdx.x;
    const int wave = t >> 6, lane = t & 63;
    const int quad = lane >> 4, c = lane & 15;
    const int wrow = (wave >> 1) * 32, wcol = (wave & 1) * 32;

    const v4f zero4 = {0.f, 0.f, 0.f, 0.f};
    v4f acc[2][2];
    acc[0][0] = zero4; acc[0][1] = zero4; acc[1][0] = zero4; acc[1][1] = zero4;

    const int sr = t >> 2, sch = t & 3;

    for (int k0 = 0; k0 < 512; k0 += 32) {
        bfx8 h, l;
        split8(A + (long)(mbase + sr) * 512 + k0 + sch * 8, h, l);
        *(bfx8*)(&Ah[sr][sch * 8]) = h;
        *(bfx8*)(&Al[sr][sch * 8]) = l;
        *(bfx8*)(&Bh[sr][sch * 8]) = *(const bfx8*)(BTh + (long)(nbase + sr) * 512 + k0 + sch * 8);
        *(bfx8*)(&Bl[sr][sch * 8]) = *(const bfx8*)(BTl + (long)(nbase + sr) * 512 + k0 + sch * 8);
        __syncthreads();

        bfx8 ah0 = *(const bfx8*)(&Ah[wrow + c][quad * 8]);
        bfx8 ah1 = *(const bfx8*)(&Ah[wrow + 16 + c][quad * 8]);
        bfx8 al0 = *(const bfx8*)(&Al[wrow + c][quad * 8]);
        bfx8 al1 = *(const bfx8*)(&Al[wrow + 16 + c][quad * 8]);
        bfx8 bh0 = *(const bfx8*)(&Bh[wcol + c][quad * 8]);
        bfx8 bh1 = *(const bfx8*)(&Bh[wcol + 16 + c][quad * 8]);
        bfx8 bl0 = *(const bfx8*)(&Bl[wcol + c][quad * 8]);
        bfx8 bl1 = *(const bfx8*)(&Bl[wcol + 16 + c][quad * 8]);
        acc[0][0] = mfma16(ah0, bh0, acc[0][0]);
        acc[0][0] = mfma16(ah0, bl0, acc[0][0]);
        acc[0][0] = mfma16(al0, bh0, acc[0][0]);
        acc[0][1] = mfma16(ah0, bh1, acc[0][1]);
        acc[0][1] = mfma16(ah0, bl1, acc[0][1]);
        acc[0][1] = mfma16(al0, bh1, acc[0][1]);
        acc[1][0] = mfma16(ah1, bh0, acc[1][0]);
        acc[1][0] = mfma16(ah1, bl0, acc[1][0]);
        acc[1][0] = mfma16(al1, bh0, acc[1][0]);
        acc[1][1] = mfma16(ah1, bh1, acc[1][1]);
        acc[1][1] = mfma16(ah1, bl1, acc[1][1]);
        acc[1][1] = mfma16(al1, bh1, acc[1][1]);
        __syncthreads();
    }

#pragma unroll
    for (int tm = 0; tm < 2; ++tm)
#pragma unroll
        for (int tn = 0; tn < 2; ++tn)
#pragma unroll
            for (int i = 0; i < 4; ++i) {
                int row = mbase + wrow + tm * 16 + quad * 4 + i;
                int col = nbase + wcol + tn * 16 + c;
                float v = fmaxf(acc[tm][tn][i] + bias[col], 0.f);
                bf16 h = (bf16)v;
                Ch[(long)row * 512 + col] = h;
                Cl[(long)row * 512 + col] = (bf16)(v - (float)h);
            }
}

// ---------------------------------------------------------------------------
// mix gate + lengths + packed mask bitmasks: one wave per (n,q) row.
// ---------------------------------------------------------------------------
__global__ __launch_bounds__(256) void mix_len_kernel(
    const float* __restrict__ Q, const int* __restrict__ mask,
    const float* __restrict__ mix_w, const float* __restrict__ mix_b,
    float* __restrict__ mixv, float* __restrict__ stepv, float* __restrict__ lenv,
    unsigned* __restrict__ maskbits) {
    int row = blockIdx.x * 4 + (threadIdx.x >> 6);
    int lane = threadIdx.x & 63;
    float dot = 0.f, ms = 0.f;
    unsigned myw = 0;
#pragma unroll
    for (int j = 0; j < 8; ++j) {
        float qv = Q[(long)row * 512 + j * 64 + lane];
        float wv = mix_w[j * 64 + lane];
        dot += qv * wv;
        int mv = mask[(long)row * 512 + j * 64 + lane];
        unsigned long long b = __ballot(mv != 0);
        ms += (float)__popcll(b);
        if ((lane >> 1) == j) myw = (unsigned)(b >> ((lane & 1) * 32));
    }
#pragma unroll
    for (int o = 32; o > 0; o >>= 1) dot += __shfl_xor(dot, o);
    if (lane < 16) maskbits[(long)row * 16 + lane] = myw;
    if (lane == 0) {
        mixv[row] = sigm(dot + mix_b[0]);
        lenv[row] = ms;
        stepv[row] = 1.0f / fmaxf(1.0f, ms - 1.0f);
    }
}

// ---------------------------------------------------------------------------
// Fused GRU (as r7): 64 rows/block of one (n,hd); split Xg + split hp.
// ---------------------------------------------------------------------------
__global__ __launch_bounds__(256) void gru_fused_kernel(
    const bf16* __restrict__ Xh, const bf16* __restrict__ Xl,
    const float* __restrict__ hp,
    const bf16* __restrict__ wih, const bf16* __restrict__ wil,
    const bf16* __restrict__ whh, const bf16* __restrict__ whl,
    const float* __restrict__ gbi, const float* __restrict__ gbh,
    const float* __restrict__ pa, const float* __restrict__ Wsigma,
    const float* __restrict__ Wrho,
    const float* __restrict__ lenv, const float* __restrict__ stepv,
    float* __restrict__ muv, float* __restrict__ sigv) {
    __shared__ bf16 Wh[192][72], Wl[192][72];
    __shared__ float biL[384];

    const int b = blockIdx.x;
    const int qb = b & 7, nh = b >> 3, hd = nh & 7, n = nh >> 3;
    const int t = threadIdx.x;
    const int w = t >> 6, lane = t & 63, quad = lane >> 4, c = lane & 15;
    const int q0 = qb * 64 + w * 16;

    if (t < 192) { biL[t] = gbi[t]; biL[192 + t] = gbh[t]; }
#pragma unroll
    for (int it = 0; it < 6; ++it) {
        int task = it * 256 + t;
        int r = task >> 3, ch = task & 7;
        *(bfx8*)(&Wh[r][ch * 8]) = *(const bfx8*)(wih + r * 64 + ch * 8);
        *(bfx8*)(&Wl[r][ch * 8]) = *(const bfx8*)(wil + r * 64 + ch * 8);
    }
    __syncthreads();

    const v4f zero4 = {0.f, 0.f, 0.f, 0.f};
    v4f gi[12], gh[12];
#pragma unroll
    for (int nt = 0; nt < 12; ++nt) gi[nt] = zero4;
#pragma unroll
    for (int ks = 0; ks < 2; ++ks) {
        long ao = (long)(n * 512 + q0 + c) * 512 + hd * 64 + ks * 32 + quad * 8;
        bfx8 xh = *(const bfx8*)(Xh + ao);
        bfx8 xl = *(const bfx8*)(Xl + ao);
#pragma unroll
        for (int nt = 0; nt < 12; ++nt) {
            bfx8 bh = *(const bfx8*)(&Wh[nt * 16 + c][ks * 32 + quad * 8]);
            bfx8 bl = *(const bfx8*)(&Wl[nt * 16 + c][ks * 32 + quad * 8]);
            gi[nt] = mfma16(xh, bh, gi[nt]);
            gi[nt] = mfma16(xh, bl, gi[nt]);
            gi[nt] = mfma16(xl, bh, gi[nt]);
        }
    }
    __syncthreads();
#pragma unroll
    for (int it = 0; it < 6; ++it) {
        int task = it * 256 + t;
        int r = task >> 3, ch = task & 7;
        *(bfx8*)(&Wh[r][ch * 8]) = *(const bfx8*)(whh + r * 64 + ch * 8);
        *(bfx8*)(&Wl[r][ch * 8]) = *(const bfx8*)(whl + r * 64 + ch * 8);
    }
    __syncthreads();
#pragma unroll
    for (int nt = 0; nt < 12; ++nt) gh[nt] = zero4;
#pragma unroll
    for (int ks = 0; ks < 2; ++ks) {
        bfx8 ah, al;
        split8(hp + (long)(nh * 512 + q0 + c) * 64 + ks * 32 + quad * 8, ah, al);
#pragma unroll
        for (int nt = 0; nt < 12; ++nt) {
            bfx8 bh = *(const bfx8*)(&Wh[nt * 16 + c][ks * 32 + quad * 8]);
            bfx8 bl = *(const bfx8*)(&Wl[nt * 16 + c][ks * 32 + quad * 8]);
            gh[nt] = mfma16(ah, bh, gh[nt]);
            gh[nt] = mfma16(ah, bl, gh[nt]);
            gh[nt] = mfma16(al, bh, gh[nt]);
        }
    }

    float st[4][4];
#pragma unroll
    for (int t4 = 0; t4 < 4; ++t4) {
        float bir = biL[t4 * 16 + c];
        float biz = biL[64 + t4 * 16 + c];
        float bin = biL[128 + t4 * 16 + c];
        float bhr = biL[192 + t4 * 16 + c];
        float bhz = biL[256 + t4 * 16 + c];
        float bhn = biL[320 + t4 * 16 + c];
#pragma unroll
        for (int i = 0; i < 4; ++i) {
            int row = q0 + quad * 4 + i;
            float r = sigm(gi[t4][i] + bir + gh[t4][i] + bhr);
            float z = sigm(gi[t4 + 4][i] + biz + gh[t4 + 4][i] + bhz);
            float nn_ = tanhf(gi[t4 + 8][i] + bin + r * (gh[t4 + 8][i] + bhn));
            float hpv = hp[(long)(nh * 512 + row) * 64 + t4 * 16 + c];
            st[t4][i] = (1.0f - z) * nn_ + z * hpv;
        }
    }

    float ws_[4], wr0[4], wr1[4], wr2[4];
#pragma unroll
    for (int t4 = 0; t4 < 4; ++t4) {
        int d = t4 * 16 + c;
        ws_[t4] = Wsigma[hd * 64 + d];
        wr0[t4] = Wrho[(hd * 64 + d) * 3 + 0];
        wr1[t4] = Wrho[(hd * 64 + d) * 3 + 1];
        wr2[t4] = Wrho[(hd * 64 + d) * 3 + 2];
    }
#pragma unroll
    for (int i = 0; i < 4; ++i) {
        float s0 = 0.f, s1 = 0.f, s2 = 0.f, s3 = 0.f;
#pragma unroll
        for (int t4 = 0; t4 < 4; ++t4) {
            float sv = st[t4][i];
            s0 += sv * ws_[t4];
            s1 += sv * wr0[t4];
            s2 += sv * wr1[t4];
            s3 += sv * wr2[t4];
        }
#pragma unroll
        for (int o = 1; o < 16; o <<= 1) {
            s0 += __shfl_xor(s0, o);
            s1 += __shfl_xor(s1, o);
            s2 += __shfl_xor(s2, o);
            s3 += __shfl_xor(s3, o);
        }
        if (c == 0) {
            int row = q0 + quad * 4 + i;
            int idx = nh * 512 + row, rq = n * 512 + row;
            float L = lenv[rq], sp = stepv[rq];
            float sg = (fmaxf(s0, 0.f) + 0.27f) / L;
            float fl = floorf(s1);
            float steps = fl + sigm(10.0f * (fabsf(s1 - fl) - 0.5f));
            float ag = sigm(s2), bg = sigm(s3);
            float mu_ = steps * sp + ag * pa[idx] + bg;
            float mu = fmaxf(0.01f * mu_, fminf(mu_, 1.0f + 0.01f * mu_));
            muv[idx] = mu;
            sigv[idx] = sg;
        }
    }
}

// ---------------------------------------------------------------------------
// Fused attention v3: per block (n,hd,16-q tile). K/V fragments loaded
// DIRECTLY from global (per-wave disjoint ownership -> no LDS staging, no
// staging barriers). LDS only for Plds (C->A transform), vps, mask words,
// reductions (~22.5 KB). __expf for all exponentials.
// Wave w owns keys [w*128, w*128+128) and v-cols [w*16, w*16+16).
// ---------------------------------------------------------------------------
__global__ __launch_bounds__(256) void attn_fused_kernel(
    const bf16* __restrict__ Qh, const bf16* __restrict__ Kh,
    const bf16* __restrict__ VhT, const unsigned* __restrict__ maskbits,
    const float* __restrict__ vpos, const float* __restrict__ mixv,
    const float* __restrict__ stepv, const float* __restrict__ muv,
    const float* __restrict__ sigv, bf16* __restrict__ att) {
    __shared__ bf16 Plds[16][520];
    __shared__ float vps[512];
    __shared__ unsigned mb[16][16];
    __shared__ float rmax[4][16], rsum[4][16], rgsum[4][16];
    __shared__ float rowmu[16], rowsig[16], rowstep[16], rowmix[16];

    const int b = blockIdx.x;
    const int qt = b & 31, nh = b >> 5, hd = nh & 7, n = nh >> 3;
    const int t = threadIdx.x;

    if (t < 16) {
        int q = qt * 16 + t;
        int idx = nh * 512 + q, rq = n * 512 + q;
        rowmu[t] = muv[idx];
        rowsig[t] = sigv[idx];
        rowstep[t] = stepv[rq];
        rowmix[t] = mixv[rq];
    }
    vps[t] = vpos[t];
    vps[256 + t] = vpos[256 + t];
    mb[t >> 4][t & 15] = maskbits[(long)(n * 512 + qt * 16 + (t >> 4)) * 16 + (t & 15)];

    const int wave = t >> 6, lane = t & 63;
    const int quad = lane >> 4, c = lane & 15;
    const int qloc = quad * 4;

    // Q fragments direct (rows shared across waves; L2 absorbs re-reads)
    const bf16* qrow = Qh + (long)(n * 512 + qt * 16 + c) * 512 + hd * 64 + quad * 8;
    bfx8 afr0 = *(const bfx8*)qrow;
    bfx8 afr1 = *(const bfx8*)(qrow + 32);

    // QK^T: 8 tiles; key k = wave*128 + t8*16 + c; K fragments direct
    const v4f zero4 = {0.f, 0.f, 0.f, 0.f};
    v4f acc[8];
#pragma unroll
    for (int i = 0; i < 8; ++i) acc[i] = zero4;

    const bf16* kbase = Kh + (long)(n * 512 + wave * 128 + c) * 512 + hd * 64 + quad * 8;
#pragma unroll
    for (int t8 = 0; t8 < 8; ++t8) {
        bfx8 b0 = *(const bfx8*)(kbase + (long)t8 * 16 * 512);
        bfx8 b1 = *(const bfx8*)(kbase + (long)t8 * 16 * 512 + 32);
        acc[t8] = mfma16(afr0, b0, acc[t8]);
        acc[t8] = mfma16(afr1, b1, acc[t8]);
    }
#pragma unroll
    for (int t8 = 0; t8 < 8; ++t8) acc[t8] = acc[t8] * 0.125f;  // D^-0.5

    __syncthreads();  // #1: mb/vps/rowstats visible

    // per-row mask bits for this lane's 8 keys (bit t8)
    unsigned mbits[4] = {0u, 0u, 0u, 0u};
#pragma unroll
    for (int t8 = 0; t8 < 8; ++t8) {
        int wd = wave * 4 + (t8 >> 1);
        int bit = (t8 & 1) * 16 + c;
#pragma unroll
        for (int i = 0; i < 4; ++i)
            mbits[i] |= ((mb[qloc + i][wd] >> bit) & 1u) << t8;
    }

    // row max
#pragma unroll
    for (int i = 0; i < 4; ++i) {
        float mx = -3.0e38f;
#pragma unroll
        for (int t8 = 0; t8 < 8; ++t8)
            if ((mbits[i] >> t8) & 1u) mx = fmaxf(mx, acc[t8][i]);
        mx = fmaxf(mx, __shfl_xor(mx, 1));
        mx = fmaxf(mx, __shfl_xor(mx, 2));
        mx = fmaxf(mx, __shfl_xor(mx, 4));
        mx = fmaxf(mx, __shfl_xor(mx, 8));
        if (c == 0) rmax[wave][qloc + i] = mx;
    }
    __syncthreads();  // #2

    float gmx[4], inv2s[4];
#pragma unroll
    for (int i = 0; i < 4; ++i) {
        gmx[i] = fmaxf(fmaxf(rmax[0][qloc + i], rmax[1][qloc + i]),
                       fmaxf(rmax[2][qloc + i], rmax[3][qloc + i]));
        float sg = rowsig[qloc + i];
        inv2s[i] = 0.5f / (sg * sg);
    }

    // pass 1: sums (pv/gv recomputed later; __expf is cheap)
    float psum[4] = {0.f, 0.f, 0.f, 0.f};
    float gsum[4] = {0.f, 0.f, 0.f, 0.f};
#pragma unroll
    for (int t8 = 0; t8 < 8; ++t8) {
        int k = wave * 128 + t8 * 16 + c;
        float vp = vps[k];
#pragma unroll
        for (int i = 0; i < 4; ++i) {
            int on = (mbits[i] >> t8) & 1;
            float pv = on ? __expf(acc[t8][i] - gmx[i]) : 0.f;
            float d = vp * rowstep[qloc + i] - rowmu[qloc + i];
            float gv = on ? __expf(-(d * d) * inv2s[i]) : 0.f;
            psum[i] += pv;
            gsum[i] += gv;
        }
    }
#pragma unroll
    for (int i = 0; i < 4; ++i) {
#pragma unroll
        for (int o = 1; o < 16; o <<= 1) {
            psum[i] += __shfl_xor(psum[i], o);
            gsum[i] += __shfl_xor(gsum[i], o);
        }
        if (c == 0) {
            rsum[wave][qloc + i] = psum[i];
            rgsum[wave][qloc + i] = gsum[i];
        }
    }
    __syncthreads();  // #3

    float ac[4], bc[4];
#pragma unroll
    for (int i = 0; i < 4; ++i) {
        float Sp = rsum[0][qloc + i] + rsum[1][qloc + i] + rsum[2][qloc + i] + rsum[3][qloc + i];
        float Sg = rgsum[0][qloc + i] + rgsum[1][qloc + i] + rgsum[2][qloc + i] +
                   rgsum[3][qloc + i] + 512.0f * 1e-20f;
        float m_ = rowmix[qloc + i];
        ac[i] = (1.0f - m_) / Sp;
        bc[i] = m_ / Sg;
    }

    // combine -> Plds (C-layout rows -> A-layout via LDS)
#pragma unroll
    for (int t8 = 0; t8 < 8; ++t8) {
        int k = wave * 128 + t8 * 16 + c;
        float vp = vps[k];
#pragma unroll
        for (int i = 0; i < 4; ++i) {
            int on = (mbits[i] >> t8) & 1;
            float pv = on ? __expf(acc[t8][i] - gmx[i]) : 0.f;
            float d = vp * rowstep[qloc + i] - rowmu[qloc + i];
            float gv = on ? __expf(-(d * d) * inv2s[i]) : 0.f;
            Plds[qloc + i][k] = (bf16)(pv * ac[i] + gv * bc[i]);
        }
    }
    __syncthreads();  // #4

    // PV: wave owns v-cols wave*16+c; V fragments direct from VhT
    v4f accO = zero4;
    const bf16* vrow = VhT + (long)(n * 512 + hd * 64 + wave * 16 + c) * 512 + quad * 8;
#pragma unroll
    for (int ks = 0; ks < 16; ++ks) {
        bfx8 af = *(const bfx8*)(&Plds[c][ks * 32 + quad * 8]);
        bfx8 bf_ = *(const bfx8*)(vrow + ks * 32);
        accO = mfma16(af, bf_, accO);
    }

#pragma unroll
    for (int i = 0; i < 4; ++i) {
        att[(long)(n * 512 + qt * 16 + quad * 4 + i) * 512 + hd * 64 + wave * 16 + c] =
            (bf16)accO[i];
    }
}

// ---------------------------------------------------------------------------
extern "C" void kernel_launch(void* const* d_in, const int* in_sizes, int n_in,
                              void* d_out, int out_size, void* d_ws, size_t ws_size,
                              hipStream_t stream) {
    (void)in_sizes; (void)n_in; (void)out_size; (void)ws_size;

    const float* Q = (const float*)d_in[0];
    const float* K = (const float*)d_in[1];
    const float* V = (const float*)d_in[2];
    const float* past_state = (const float*)d_in[3];
    const float* past_att = (const float*)d_in[4];
    const float* vpos = (const float*)d_in[5];
    const int* mask = (const int*)d_in[6];
    const float* Wq = (const float*)d_in[7];
    const float* Wk = (const float*)d_in[8];
    const float* Wv = (const float*)d_in[9];
    const float* Wpos = (const float*)d_in[10];
    const float* bpos = (const float*)d_in[11];
    const float* Wsigma = (const float*)d_in[12];
    const float* Wrho = (const float*)d_in[13];
    const float* mix_w = (const float*)d_in[14];
    const float* mix_b = (const float*)d_in[15];
    const float* gwi = (const float*)d_in[16];
    const float* gwh = (const float*)d_in[17];
    const float* gbi = (const float*)d_in[18];
    const float* gbh = (const float*)d_in[19];
    const float* Wc = (const float*)d_in[20];
    float* out = (float*)d_out;

    // ---- workspace ----
    char* p = (char*)d_ws;
    const size_t SZB = 8192UL * 512 * 2;
    const size_t SZW = 512UL * 512 * 2;
    bf16* Qc = (bf16*)p;    p += SZB;
    bf16* Kc = (bf16*)p;    p += SZB;
    bf16* Vc = (bf16*)p;    p += SZB;
    bf16* WqT = (bf16*)p;   p += SZW;
    bf16* WkT = (bf16*)p;   p += SZW;
    bf16* WvT = (bf16*)p;   p += SZW;
    bf16* WpT = (bf16*)p;   p += SZW;
    bf16* WpTl = (bf16*)p;  p += SZW;
    bf16* WcT = (bf16*)p;   p += SZW;
    bf16* wih = (bf16*)p;   p += 24576;
    bf16* wil = (bf16*)p;   p += 24576;
    bf16* whh = (bf16*)p;   p += 24576;
    bf16* whl = (bf16*)p;   p += 24576;
    bf16* Qh = (bf16*)p;    p += SZB;
    bf16* Kh = (bf16*)p;    p += SZB;
    bf16* VhT = (bf16*)p;   p += SZB;
    bf16* Xh = (bf16*)p;
    bf16* att = Xh;         p += SZB;
    bf16* Xl = (bf16*)p;    p += SZB;
    unsigned* maskbits = (unsigned*)p;   p += 8192UL * 16 * 4;
    float* mixv = (float*)p;  p += 32768;
    float* stepv = (float*)p; p += 32768;
    float* lenv = (float*)p;  p += 32768;
    float* muv = (float*)p;   p += 262144;
    float* sigv = (float*)p;  p += 262144;

    dim3 blk(256);
    dim3 gProj(128, 8, 1);

    conv_qkv_kernel<<<dim3(6144), blk, 0, stream>>>(Q, K, V, Qc, Kc, Vc);

    TW tw;
    tw.src[0] = Wq; tw.src[1] = Wk; tw.src[2] = Wv; tw.src[3] = Wpos; tw.src[4] = Wc;
    tw.dst[0] = WqT; tw.dst[1] = WkT; tw.dst[2] = WvT; tw.dst[3] = WpT; tw.dst[4] = WcT;
    tw.dstlo[0] = nullptr; tw.dstlo[1] = nullptr; tw.dstlo[2] = nullptr;
    tw.dstlo[3] = WpTl; tw.dstlo[4] = nullptr;
    trans_w_kernel<<<dim3(64, 5), blk, 0, stream>>>(tw);

    gru_prep_kernel<<<dim3(2), dim3(192), 0, stream>>>(gwi, gwh, wih, wil, whh, whl);

    G3 g;
    g.A[0] = Qc; g.A[1] = Kc; g.A[2] = Vc;
    g.BT[0] = WqT; g.BT[1] = WkT; g.BT[2] = WvT;
    g.C[0] = Qh; g.C[1] = Kh; g.C[2] = VhT;
    gemm_bt3<<<dim3(128, 8, 3), blk, 0, stream>>>(g);

    gemm_split_hl<<<gProj, blk, 0, stream>>>(Q, WpT, WpTl, bpos, Xh, Xl);

    mix_len_kernel<<<dim3(2048), blk, 0, stream>>>(Q, mask, mix_w, mix_b, mixv, stepv, lenv, maskbits);

    gru_fused_kernel<<<dim3(1024), blk, 0, stream>>>(
        Xh, Xl, past_state, wih, wil, whh, whl, gbi, gbh, past_att, Wsigma, Wrho,
        lenv, stepv, muv, sigv);

    attn_fused_kernel<<<dim3(4096), blk, 0, stream>>>(
        Qh, Kh, VhT, maskbits, vpos, mixv, stepv, muv, sigv, att);

    gemm_out<<<gProj, blk, 0, stream>>>(att, WcT, out);
}

// Round 9
// 361.584 us; speedup vs baseline: 1.7375x; 1.0119x over previous
//
#include <hip/hip_runtime.h>

// ---------------------------------------------------------------------------
// Multiheaded_GRUMix_Attention on MI355X (gfx950). Inputs f32, output f32.
//
// R9: (1) attn stores pv/gv as packed bf16 pairs in VGPRs -> no exp recompute
// in the combine pass (r8 had 128 __expf/thread); (2) XCD-aware block swizzle
// keeps all 32 q-tiles of an (n,hd) on one XCD (K/V hot in its L2);
// (3) conv_qkv deleted -- gemm_bt3 stages f32 A directly with in-staging
// convert; (4) fast tanh in GRU.
// ---------------------------------------------------------------------------

typedef __bf16 bf16;
typedef __bf16 bfx8 __attribute__((ext_vector_type(8)));
typedef float v4f __attribute__((ext_vector_type(4)));

__device__ inline float sigm(float x) { return 1.0f / (1.0f + __expf(-x)); }
__device__ inline float tanh_fast(float x) { return 1.0f - 2.0f / (__expf(2.0f * x) + 1.0f); }

__device__ inline v4f mfma16(bfx8 a, bfx8 b, v4f c) {
    return __builtin_amdgcn_mfma_f32_16x16x32_bf16(a, b, c, 0, 0, 0);
}

__device__ inline void split8(const float* __restrict__ p, bfx8& hi, bfx8& lo) {
    float4 x = *(const float4*)p;
    float4 y = *(const float4*)(p + 4);
    float v[8] = {x.x, x.y, x.z, x.w, y.x, y.y, y.z, y.w};
#pragma unroll
    for (int j = 0; j < 8; ++j) {
        bf16 h = (bf16)v[j];
        hi[j] = h;
        lo[j] = (bf16)(v[j] - (float)h);
    }
}

__device__ inline bfx8 cvt8(const float* __restrict__ p) {
    float4 x = *(const float4*)p;
    float4 y = *(const float4*)(p + 4);
    bfx8 o;
    o[0] = (bf16)x.x; o[1] = (bf16)x.y; o[2] = (bf16)x.z; o[3] = (bf16)x.w;
    o[4] = (bf16)y.x; o[5] = (bf16)y.y; o[6] = (bf16)y.z; o[7] = (bf16)y.w;
    return o;
}

__device__ inline unsigned short bfbits(float v) {
    bf16 h = (bf16)v;
    return __builtin_bit_cast(unsigned short, h);
}
__device__ inline float bffrom(unsigned short u) {
    return (float)__builtin_bit_cast(bf16, u);
}

// ---------------------------------------------------------------------------
// Prep: transpose-convert weights [512][512] f32 -> bf16 W^T[col][k];
// optional lo plane for split-precision consumers (Wpos).
// ---------------------------------------------------------------------------
struct TW { const float* src[5]; bf16* dst[5]; bf16* dstlo[5]; };

__global__ __launch_bounds__(256) void trans_w_kernel(TW a) {
    __shared__ float tile[64][68];
    const float* src = a.src[blockIdx.y];
    bf16* dst = a.dst[blockIdx.y];
    bf16* dlo = a.dstlo[blockIdx.y];
    const int rbase = (blockIdx.x >> 3) * 64, cbase = (blockIdx.x & 7) * 64;
    const int t = threadIdx.x;
    const int r = t >> 2, cc = (t & 3) * 16;
    {
        const float* p = src + (long)(rbase + r) * 512 + cbase + cc;
        *(float4*)(&tile[r][cc]) = *(const float4*)p;
        *(float4*)(&tile[r][cc + 4]) = *(const float4*)(p + 4);
        *(float4*)(&tile[r][cc + 8]) = *(const float4*)(p + 8);
        *(float4*)(&tile[r][cc + 12]) = *(const float4*)(p + 12);
    }
    __syncthreads();
    {
        bfx8 h0, h1, l0, l1;
#pragma unroll
        for (int j = 0; j < 8; ++j) {
            float v0 = tile[cc + j][r];
            float v1 = tile[cc + 8 + j][r];
            bf16 a0 = (bf16)v0, a1 = (bf16)v1;
            h0[j] = a0; l0[j] = (bf16)(v0 - (float)a0);
            h1[j] = a1; l1[j] = (bf16)(v1 - (float)a1);
        }
        bf16* p = dst + (long)(cbase + r) * 512 + rbase + cc;
        *(bfx8*)p = h0;
        *(bfx8*)(p + 8) = h1;
        if (dlo) {
            bf16* pl = dlo + (long)(cbase + r) * 512 + rbase + cc;
            *(bfx8*)pl = l0;
            *(bfx8*)(pl + 8) = l1;
        }
    }
}

// ---------------------------------------------------------------------------
// Prep: GRU weights [64][192] f32 -> split-transposed bf16 [192][64] hi/lo.
// ---------------------------------------------------------------------------
__global__ void gru_prep_kernel(const float* __restrict__ gwi, const float* __restrict__ gwh,
                                bf16* ih, bf16* il, bf16* hh, bf16* hl) {
    const float* src = blockIdx.x ? gwh : gwi;
    bf16* dh = blockIdx.x ? hh : ih;
    bf16* dl = blockIdx.x ? hl : il;
    int n = threadIdx.x;
    for (int k = 0; k < 64; ++k) {
        float v = src[k * 192 + n];
        bf16 h = (bf16)v;
        dh[n * 64 + k] = h;
        dl[n * 64 + k] = (bf16)(v - (float)h);
    }
}

// ---------------------------------------------------------------------------
// 3 projection GEMMs in one launch: C[M,N] = bf16(A_f32)[M,K] @ BT[N,K]^T.
// A is f32, converted during staging. z=2 (V) writes C^T (VhT).
// ---------------------------------------------------------------------------
struct G3 { const float* A[3]; const bf16* BT[3]; bf16* C[3]; };

__global__ __launch_bounds__(256) void gemm_bt3(G3 g) {
    __shared__ bf16 As[64][72];
    __shared__ bf16 Bs[64][72];

    const int z = blockIdx.z;
    const float* __restrict__ A = g.A[z];
    const bf16* __restrict__ BT = g.BT[z];
    bf16* __restrict__ C = g.C[z];

    const int mbase = blockIdx.x * 64, nbase = blockIdx.y * 64;
    const int t = threadIdx.x;
    const int wave = t >> 6, lane = t & 63;
    const int quad = lane >> 4, c = lane & 15;
    const int wrow = (wave >> 1) * 32, wcol = (wave & 1) * 32;

    const v4f zero4 = {0.f, 0.f, 0.f, 0.f};
    v4f acc[2][2];
    acc[0][0] = zero4; acc[0][1] = zero4; acc[1][0] = zero4; acc[1][1] = zero4;

    const int sr = t >> 2, sch = t & 3;

    for (int k0 = 0; k0 < 512; k0 += 32) {
        bfx8 va = cvt8(A + (long)(mbase + sr) * 512 + k0 + sch * 8);
        bfx8 vb = *(const bfx8*)(BT + (long)(nbase + sr) * 512 + k0 + sch * 8);
        *(bfx8*)(&As[sr][sch * 8]) = va;
        *(bfx8*)(&Bs[sr][sch * 8]) = vb;
        __syncthreads();

        bfx8 a0 = *(const bfx8*)(&As[wrow + c][quad * 8]);
        bfx8 a1 = *(const bfx8*)(&As[wrow + 16 + c][quad * 8]);
        bfx8 b0 = *(const bfx8*)(&Bs[wcol + c][quad * 8]);
        bfx8 b1 = *(const bfx8*)(&Bs[wcol + 16 + c][quad * 8]);
        acc[0][0] = mfma16(a0, b0, acc[0][0]);
        acc[0][1] = mfma16(a0, b1, acc[0][1]);
        acc[1][0] = mfma16(a1, b0, acc[1][0]);
        acc[1][1] = mfma16(a1, b1, acc[1][1]);
        __syncthreads();
    }

    if (z == 2) {
#pragma unroll
        for (int tm = 0; tm < 2; ++tm)
#pragma unroll
            for (int tn = 0; tn < 2; ++tn)
#pragma unroll
                for (int i = 0; i < 4; ++i) {
                    int rl = wrow + tm * 16 + quad * 4 + i;
                    int cl = wcol + tn * 16 + c;
                    As[cl][rl] = (bf16)acc[tm][tn][i];
                }
        __syncthreads();
        bf16* CT = C + ((long)(mbase >> 9)) * 262144 + (long)nbase * 512 + (mbase & 511);
        const int rr = t >> 2, kc = (t & 3) * 16;
        bfx8 o0, o1;
#pragma unroll
        for (int j = 0; j < 8; ++j) { o0[j] = As[rr][kc + j]; o1[j] = As[rr][kc + 8 + j]; }
        *(bfx8*)(CT + (long)rr * 512 + kc) = o0;
        *(bfx8*)(CT + (long)rr * 512 + kc + 8) = o1;
    } else {
#pragma unroll
        for (int tm = 0; tm < 2; ++tm)
#pragma unroll
            for (int tn = 0; tn < 2; ++tn)
#pragma unroll
                for (int i = 0; i < 4; ++i) {
                    int row = mbase + wrow + tm * 16 + quad * 4 + i;
                    int col = nbase + wcol + tn * 16 + c;
                    C[(long)row * 512 + col] = (bf16)acc[tm][tn][i];
                }
    }
}

// ---------------------------------------------------------------------------
// Out GEMM: C[M,N] = A[M,K] @ BT[N,K]^T, f32 out.
// ---------------------------------------------------------------------------
__global__ __launch_bounds__(256) void gemm_out(
    const bf16* __restrict__ A, const bf16* __restrict__ BT, float* __restrict__ C) {
    __shared__ bf16 As[64][72];
    __shared__ bf16 Bs[64][72];

    const int mbase = blockIdx.x * 64, nbase = blockIdx.y * 64;
    const int t = threadIdx.x;
    const int wave = t >> 6, lane = t & 63;
    const int quad = lane >> 4, c = lane & 15;
    const int wrow = (wave >> 1) * 32, wcol = (wave & 1) * 32;

    const v4f zero4 = {0.f, 0.f, 0.f, 0.f};
    v4f acc[2][2];
    acc[0][0] = zero4; acc[0][1] = zero4; acc[1][0] = zero4; acc[1][1] = zero4;

    const int sr = t >> 2, sch = t & 3;

    for (int k0 = 0; k0 < 512; k0 += 32) {
        bfx8 va = *(const bfx8*)(A + (long)(mbase + sr) * 512 + k0 + sch * 8);
        bfx8 vb = *(const bfx8*)(BT + (long)(nbase + sr) * 512 + k0 + sch * 8);
        *(bfx8*)(&As[sr][sch * 8]) = va;
        *(bfx8*)(&Bs[sr][sch * 8]) = vb;
        __syncthreads();

        bfx8 a0 = *(const bfx8*)(&As[wrow + c][quad * 8]);
        bfx8 a1 = *(const bfx8*)(&As[wrow + 16 + c][quad * 8]);
        bfx8 b0 = *(const bfx8*)(&Bs[wcol + c][quad * 8]);
        bfx8 b1 = *(const bfx8*)(&Bs[wcol + 16 + c][quad * 8]);
        acc[0][0] = mfma16(a0, b0, acc[0][0]);
        acc[0][1] = mfma16(a0, b1, acc[0][1]);
        acc[1][0] = mfma16(a1, b0, acc[1][0]);
        acc[1][1] = mfma16(a1, b1, acc[1][1]);
        __syncthreads();
    }

#pragma unroll
    for (int tm = 0; tm < 2; ++tm)
#pragma unroll
        for (int tn = 0; tn < 2; ++tn)
#pragma unroll
            for (int i = 0; i < 4; ++i) {
                int row = mbase + wrow + tm * 16 + quad * 4 + i;
                int col = nbase + wcol + tn * 16 + c;
                C[(long)row * 512 + col] = acc[tm][tn][i];
            }
}

// ---------------------------------------------------------------------------
// Split-bf16 GEMM for Xg: C = relu(A@B+bias), A f32 (split in-kernel),
// B = BT hi/lo planes. Output stored as hi+lo bf16 pair.
// ---------------------------------------------------------------------------
__global__ __launch_bounds__(256) void gemm_split_hl(
    const float* __restrict__ A, const bf16* __restrict__ BTh,
    const bf16* __restrict__ BTl, const float* __restrict__ bias,
    bf16* __restrict__ Ch, bf16* __restrict__ Cl) {
    __shared__ bf16 Ah[64][72], Al[64][72];
    __shared__ bf16 Bh[64][72], Bl[64][72];

    const int mbase = blockIdx.x * 64, nbase = blockIdx.y * 64;
    const int t = threadIdx.x;
    const int wave = t >> 6, lane = t & 63;
    const int quad = lane >> 4, c = lane & 15;
    const int wrow = (wave >> 1) * 32, wcol = (wave & 1) * 32;

    const v4f zero4 = {0.f, 0.f, 0.f, 0.f};
    v4f acc[2][2];
    acc[0][0] = zero4; acc[0][1] = zero4; acc[1][0] = zero4; acc[1][1] = zero4;

    const int sr = t >> 2, sch = t & 3;

    for (int k0 = 0; k0 < 512; k0 += 32) {
        bfx8 h, l;
        split8(A + (long)(mbase + sr) * 512 + k0 + sch * 8, h, l);
        *(bfx8*)(&Ah[sr][sch * 8]) = h;
        *(bfx8*)(&Al[sr][sch * 8]) = l;
        *(bfx8*)(&Bh[sr][sch * 8]) = *(const bfx8*)(BTh + (long)(nbase + sr) * 512 + k0 + sch * 8);
        *(bfx8*)(&Bl[sr][sch * 8]) = *(const bfx8*)(BTl + (long)(nbase + sr) * 512 + k0 + sch * 8);
        __syncthreads();

        bfx8 ah0 = *(const bfx8*)(&Ah[wrow + c][quad * 8]);
        bfx8 ah1 = *(const bfx8*)(&Ah[wrow + 16 + c][quad * 8]);
        bfx8 al0 = *(const bfx8*)(&Al[wrow + c][quad * 8]);
        bfx8 al1 = *(const bfx8*)(&Al[wrow + 16 + c][quad * 8]);
        bfx8 bh0 = *(const bfx8*)(&Bh[wcol + c][quad * 8]);
        bfx8 bh1 = *(const bfx8*)(&Bh[wcol + 16 + c][quad * 8]);
        bfx8 bl0 = *(const bfx8*)(&Bl[wcol + c][quad * 8]);
        bfx8 bl1 = *(const bfx8*)(&Bl[wcol + 16 + c][quad * 8]);
        acc[0][0] = mfma16(ah0, bh0, acc[0][0]);
        acc[0][0] = mfma16(ah0, bl0, acc[0][0]);
        acc[0][0] = mfma16(al0, bh0, acc[0][0]);
        acc[0][1] = mfma16(ah0, bh1, acc[0][1]);
        acc[0][1] = mfma16(ah0, bl1, acc[0][1]);
        acc[0][1] = mfma16(al0, bh1, acc[0][1]);
        acc[1][0] = mfma16(ah1, bh0, acc[1][0]);
        acc[1][0] = mfma16(ah1, bl0, acc[1][0]);
        acc[1][0] = mfma16(al1, bh0, acc[1][0]);
        acc[1][1] = mfma16(ah1, bh1, acc[1][1]);
        acc[1][1] = mfma16(ah1, bl1, acc[1][1]);
        acc[1][1] = mfma16(al1, bh1, acc[1][1]);
        __syncthreads();
    }

#pragma unroll
    for (int tm = 0; tm < 2; ++tm)
#pragma unroll
        for (int tn = 0; tn < 2; ++tn)
#pragma unroll
            for (int i = 0; i < 4; ++i) {
                int row = mbase + wrow + tm * 16 + quad * 4 + i;
                int col = nbase + wcol + tn * 16 + c;
                float v = fmaxf(acc[tm][tn][i] + bias[col], 0.f);
                bf16 h = (bf16)v;
                Ch[(long)row * 512 + col] = h;
                Cl[(long)row * 512 + col] = (bf16)(v - (float)h);
            }
}

// ---------------------------------------------------------------------------
// mix gate + lengths + packed mask bitmasks: one wave per (n,q) row.
// ---------------------------------------------------------------------------
__global__ __launch_bounds__(256) void mix_len_kernel(
    const float* __restrict__ Q, const int* __restrict__ mask,
    const float* __restrict__ mix_w, const float* __restrict__ mix_b,
    float* __restrict__ mixv, float* __restrict__ stepv, float* __restrict__ lenv,
    unsigned* __restrict__ maskbits) {
    int row = blockIdx.x * 4 + (threadIdx.x >> 6);
    int lane = threadIdx.x & 63;
    float dot = 0.f, ms = 0.f;
    unsigned myw = 0;
#pragma unroll
    for (int j = 0; j < 8; ++j) {
        float qv = Q[(long)row * 512 + j * 64 + lane];
        float wv = mix_w[j * 64 + lane];
        dot += qv * wv;
        int mv = mask[(long)row * 512 + j * 64 + lane];
        unsigned long long b = __ballot(mv != 0);
        ms += (float)__popcll(b);
        if ((lane >> 1) == j) myw = (unsigned)(b >> ((lane & 1) * 32));
    }
#pragma unroll
    for (int o = 32; o > 0; o >>= 1) dot += __shfl_xor(dot, o);
    if (lane < 16) maskbits[(long)row * 16 + lane] = myw;
    if (lane == 0) {
        mixv[row] = sigm(dot + mix_b[0]);
        lenv[row] = ms;
        stepv[row] = 1.0f / fmaxf(1.0f, ms - 1.0f);
    }
}

// ---------------------------------------------------------------------------
// Fused GRU: 64 rows/block of one (n,hd); split Xg + split hp; fast tanh.
// ---------------------------------------------------------------------------
__global__ __launch_bounds__(256) void gru_fused_kernel(
    const bf16* __restrict__ Xh, const bf16* __restrict__ Xl,
    const float* __restrict__ hp,
    const bf16* __restrict__ wih, const bf16* __restrict__ wil,
    const bf16* __restrict__ whh, const bf16* __restrict__ whl,
    const float* __restrict__ gbi, const float* __restrict__ gbh,
    const float* __restrict__ pa, const float* __restrict__ Wsigma,
    const float* __restrict__ Wrho,
    const float* __restrict__ lenv, const float* __restrict__ stepv,
    float* __restrict__ muv, float* __restrict__ sigv) {
    __shared__ bf16 Wh[192][72], Wl[192][72];
    __shared__ float biL[384];

    const int b = blockIdx.x;
    const int qb = b & 7, nh = b >> 3, hd = nh & 7, n = nh >> 3;
    const int t = threadIdx.x;
    const int w = t >> 6, lane = t & 63, quad = lane >> 4, c = lane & 15;
    const int q0 = qb * 64 + w * 16;

    if (t < 192) { biL[t] = gbi[t]; biL[192 + t] = gbh[t]; }
#pragma unroll
    for (int it = 0; it < 6; ++it) {
        int task = it * 256 + t;
        int r = task >> 3, ch = task & 7;
        *(bfx8*)(&Wh[r][ch * 8]) = *(const bfx8*)(wih + r * 64 + ch * 8);
        *(bfx8*)(&Wl[r][ch * 8]) = *(const bfx8*)(wil + r * 64 + ch * 8);
    }
    __syncthreads();

    const v4f zero4 = {0.f, 0.f, 0.f, 0.f};
    v4f gi[12], gh[12];
#pragma unroll
    for (int nt = 0; nt < 12; ++nt) gi[nt] = zero4;
#pragma unroll
    for (int ks = 0; ks < 2; ++ks) {
        long ao = (long)(n * 512 + q0 + c) * 512 + hd * 64 + ks * 32 + quad * 8;
        bfx8 xh = *(const bfx8*)(Xh + ao);
        bfx8 xl = *(const bfx8*)(Xl + ao);
#pragma unroll
        for (int nt = 0; nt < 12; ++nt) {
            bfx8 bh = *(const bfx8*)(&Wh[nt * 16 + c][ks * 32 + quad * 8]);
            bfx8 bl = *(const bfx8*)(&Wl[nt * 16 + c][ks * 32 + quad * 8]);
            gi[nt] = mfma16(xh, bh, gi[nt]);
            gi[nt] = mfma16(xh, bl, gi[nt]);
            gi[nt] = mfma16(xl, bh, gi[nt]);
        }
    }
    __syncthreads();
#pragma unroll
    for (int it = 0; it < 6; ++it) {
        int task = it * 256 + t;
        int r = task >> 3, ch = task & 7;
        *(bfx8*)(&Wh[r][ch * 8]) = *(const bfx8*)(whh + r * 64 + ch * 8);
        *(bfx8*)(&Wl[r][ch * 8]) = *(const bfx8*)(whl + r * 64 + ch * 8);
    }
    __syncthreads();
#pragma unroll
    for (int nt = 0; nt < 12; ++nt) gh[nt] = zero4;
#pragma unroll
    for (int ks = 0; ks < 2; ++ks) {
        bfx8 ah, al;
        split8(hp + (long)(nh * 512 + q0 + c) * 64 + ks * 32 + quad * 8, ah, al);
#pragma unroll
        for (int nt = 0; nt < 12; ++nt) {
            bfx8 bh = *(const bfx8*)(&Wh[nt * 16 + c][ks * 32 + quad * 8]);
            bfx8 bl = *(const bfx8*)(&Wl[nt * 16 + c][ks * 32 + quad * 8]);
            gh[nt] = mfma16(ah, bh, gh[nt]);
            gh[nt] = mfma16(ah, bl, gh[nt]);
            gh[nt] = mfma16(al, bh, gh[nt]);
        }
    }

    float st[4][4];
#pragma unroll
    for (int t4 = 0; t4 < 4; ++t4) {
        float bir = biL[t4 * 16 + c];
        float biz = biL[64 + t4 * 16 + c];
        float bin = biL[128 + t4 * 16 + c];
        float bhr = biL[192 + t4 * 16 + c];
        float bhz = biL[256 + t4 * 16 + c];
        float bhn = biL[320 + t4 * 16 + c];
#pragma unroll
        for (int i = 0; i < 4; ++i) {
            int row = q0 + quad * 4 + i;
            float r = sigm(gi[t4][i] + bir + gh[t4][i] + bhr);
            float z = sigm(gi[t4 + 4][i] + biz + gh[t4 + 4][i] + bhz);
            float nn_ = tanh_fast(gi[t4 + 8][i] + bin + r * (gh[t4 + 8][i] + bhn));
            float hpv = hp[(long)(nh * 512 + row) * 64 + t4 * 16 + c];
            st[t4][i] = (1.0f - z) * nn_ + z * hpv;
        }
    }

    float ws_[4], wr0[4], wr1[4], wr2[4];
#pragma unroll
    for (int t4 = 0; t4 < 4; ++t4) {
        int d = t4 * 16 + c;
        ws_[t4] = Wsigma[hd * 64 + d];
        wr0[t4] = Wrho[(hd * 64 + d) * 3 + 0];
        wr1[t4] = Wrho[(hd * 64 + d) * 3 + 1];
        wr2[t4] = Wrho[(hd * 64 + d) * 3 + 2];
    }
#pragma unroll
    for (int i = 0; i < 4; ++i) {
        float s0 = 0.f, s1 = 0.f, s2 = 0.f, s3 = 0.f;
#pragma unroll
        for (int t4 = 0; t4 < 4; ++t4) {
            float sv = st[t4][i];
            s0 += sv * ws_[t4];
            s1 += sv * wr0[t4];
            s2 += sv * wr1[t4];
            s3 += sv * wr2[t4];
        }
#pragma unroll
        for (int o = 1; o < 16; o <<= 1) {
            s0 += __shfl_xor(s0, o);
            s1 += __shfl_xor(s1, o);
            s2 += __shfl_xor(s2, o);
            s3 += __shfl_xor(s3, o);
        }
        if (c == 0) {
            int row = q0 + quad * 4 + i;
            int idx = nh * 512 + row, rq = n * 512 + row;
            float L = lenv[rq], sp = stepv[rq];
            float sg = (fmaxf(s0, 0.f) + 0.27f) / L;
            float fl = floorf(s1);
            float steps = fl + sigm(10.0f * (fabsf(s1 - fl) - 0.5f));
            float ag = sigm(s2), bg = sigm(s3);
            float mu_ = steps * sp + ag * pa[idx] + bg;
            float mu = fmaxf(0.01f * mu_, fminf(mu_, 1.0f + 0.01f * mu_));
            muv[idx] = mu;
            sigv[idx] = sg;
        }
    }
}

// ---------------------------------------------------------------------------
// Fused attention v4: direct-global K/V (per-wave disjoint), packed pv/gv in
// VGPRs (single exp pass), XCD-aware swizzle (32 q-tiles of one nh -> same
// XCD). LDS ~22.5 KB, 4 barriers.
// ---------------------------------------------------------------------------
__global__ __launch_bounds__(256) void attn_fused_kernel(
    const bf16* __restrict__ Qh, const bf16* __restrict__ Kh,
    const bf16* __restrict__ VhT, const unsigned* __restrict__ maskbits,
    const float* __restrict__ vpos, const float* __restrict__ mixv,
    const float* __restrict__ stepv, const float* __restrict__ muv,
    const float* __restrict__ sigv, bf16* __restrict__ att) {
    __shared__ bf16 Plds[16][520];
    __shared__ float vps[512];
    __shared__ unsigned mb[16][16];
    __shared__ float rmax[4][16], rsum[4][16], rgsum[4][16];
    __shared__ float rowmu[16], rowsig[16], rowstep[16], rowmix[16];

    // XCD swizzle: dispatch is round-robin mod 8 XCDs; keep one nh's 32
    // q-tiles on one XCD: b = (nh>>3)*256 + qt*8 + (nh&7).
    const int b = blockIdx.x;
    const int nh = ((b >> 8) << 3) | (b & 7);
    const int qt = (b >> 3) & 31;
    const int hd = nh & 7, n = nh >> 3;
    const int t = threadIdx.x;

    if (t < 16) {
        int q = qt * 16 + t;
        int idx = nh * 512 + q, rq = n * 512 + q;
        rowmu[t] = muv[idx];
        rowsig[t] = sigv[idx];
        rowstep[t] = stepv[rq];
        rowmix[t] = mixv[rq];
    }
    vps[t] = vpos[t];
    vps[256 + t] = vpos[256 + t];
    mb[t >> 4][t & 15] = maskbits[(long)(n * 512 + qt * 16 + (t >> 4)) * 16 + (t & 15)];

    const int wave = t >> 6, lane = t & 63;
    const int quad = lane >> 4, c = lane & 15;
    const int qloc = quad * 4;

    const bf16* qrow = Qh + (long)(n * 512 + qt * 16 + c) * 512 + hd * 64 + quad * 8;
    bfx8 afr0 = *(const bfx8*)qrow;
    bfx8 afr1 = *(const bfx8*)(qrow + 32);

    const v4f zero4 = {0.f, 0.f, 0.f, 0.f};
    v4f acc[8];
#pragma unroll
    for (int i = 0; i < 8; ++i) acc[i] = zero4;

    const bf16* kbase = Kh + (long)(n * 512 + wave * 128 + c) * 512 + hd * 64 + quad * 8;
#pragma unroll
    for (int t8 = 0; t8 < 8; ++t8) {
        bfx8 b0 = *(const bfx8*)(kbase + (long)t8 * 16 * 512);
        bfx8 b1 = *(const bfx8*)(kbase + (long)t8 * 16 * 512 + 32);
        acc[t8] = mfma16(afr0, b0, acc[t8]);
        acc[t8] = mfma16(afr1, b1, acc[t8]);
    }
#pragma unroll
    for (int t8 = 0; t8 < 8; ++t8) acc[t8] = acc[t8] * 0.125f;  // D^-0.5

    __syncthreads();  // #1

    unsigned mbits[4] = {0u, 0u, 0u, 0u};
#pragma unroll
    for (int t8 = 0; t8 < 8; ++t8) {
        int wd = wave * 4 + (t8 >> 1);
        int bit = (t8 & 1) * 16 + c;
#pragma unroll
        for (int i = 0; i < 4; ++i)
            mbits[i] |= ((mb[qloc + i][wd] >> bit) & 1u) << t8;
    }

#pragma unroll
    for (int i = 0; i < 4; ++i) {
        float mx = -3.0e38f;
#pragma unroll
        for (int t8 = 0; t8 < 8; ++t8)
            if ((mbits[i] >> t8) & 1u) mx = fmaxf(mx, acc[t8][i]);
        mx = fmaxf(mx, __shfl_xor(mx, 1));
        mx = fmaxf(mx, __shfl_xor(mx, 2));
        mx = fmaxf(mx, __shfl_xor(mx, 4));
        mx = fmaxf(mx, __shfl_xor(mx, 8));
        if (c == 0) rmax[wave][qloc + i] = mx;
    }
    __syncthreads();  // #2

    float gmx[4], inv2s[4];
#pragma unroll
    for (int i = 0; i < 4; ++i) {
        gmx[i] = fmaxf(fmaxf(rmax[0][qloc + i], rmax[1][qloc + i]),
                       fmaxf(rmax[2][qloc + i], rmax[3][qloc + i]));
        float sg = rowsig[qloc + i];
        inv2s[i] = 0.5f / (sg * sg);
    }

    // single exp pass: pv/gv computed once, packed bf16 pair per score
    float psum[4] = {0.f, 0.f, 0.f, 0.f};
    float gsum[4] = {0.f, 0.f, 0.f, 0.f};
    unsigned pg[8][4];
#pragma unroll
    for (int t8 = 0; t8 < 8; ++t8) {
        int k = wave * 128 + t8 * 16 + c;
        float vp = vps[k];
#pragma unroll
        for (int i = 0; i < 4; ++i) {
            int on = (mbits[i] >> t8) & 1;
            float pv = on ? __expf(acc[t8][i] - gmx[i]) : 0.f;
            float d = vp * rowstep[qloc + i] - rowmu[qloc + i];
            float gv = on ? __expf(-(d * d) * inv2s[i]) : 0.f;
            psum[i] += pv;
            gsum[i] += gv;
            pg[t8][i] = ((unsigned)bfbits(gv) << 16) | (unsigned)bfbits(pv);
        }
    }
#pragma unroll
    for (int i = 0; i < 4; ++i) {
#pragma unroll
        for (int o = 1; o < 16; o <<= 1) {
            psum[i] += __shfl_xor(psum[i], o);
            gsum[i] += __shfl_xor(gsum[i], o);
        }
        if (c == 0) {
            rsum[wave][qloc + i] = psum[i];
            rgsum[wave][qloc + i] = gsum[i];
        }
    }
    __syncthreads();  // #3

    float ac[4], bc[4];
#pragma unroll
    for (int i = 0; i < 4; ++i) {
        float Sp = rsum[0][qloc + i] + rsum[1][qloc + i] + rsum[2][qloc + i] + rsum[3][qloc + i];
        float Sg = rgsum[0][qloc + i] + rgsum[1][qloc + i] + rgsum[2][qloc + i] +
                   rgsum[3][qloc + i] + 512.0f * 1e-20f;
        float m_ = rowmix[qloc + i];
        ac[i] = (1.0f - m_) / Sp;
        bc[i] = m_ / Sg;
    }

    // combine from packed values -> Plds (no exp recompute)
#pragma unroll
    for (int t8 = 0; t8 < 8; ++t8) {
        int k = wave * 128 + t8 * 16 + c;
#pragma unroll
        for (int i = 0; i < 4; ++i) {
            float pv = bffrom((unsigned short)(pg[t8][i] & 0xffffu));
            float gv = bffrom((unsigned short)(pg[t8][i] >> 16));
            Plds[qloc + i][k] = (bf16)(pv * ac[i] + gv * bc[i]);
        }
    }
    __syncthreads();  // #4

    v4f accO = zero4;
    const bf16* vrow = VhT + (long)(n * 512 + hd * 64 + wave * 16 + c) * 512 + quad * 8;
#pragma unroll
    for (int ks = 0; ks < 16; ++ks) {
        bfx8 af = *(const bfx8*)(&Plds[c][ks * 32 + quad * 8]);
        bfx8 bf_ = *(const bfx8*)(vrow + ks * 32);
        accO = mfma16(af, bf_, accO);
    }

#pragma unroll
    for (int i = 0; i < 4; ++i) {
        att[(long)(n * 512 + qt * 16 + quad * 4 + i) * 512 + hd * 64 + wave * 16 + c] =
            (bf16)accO[i];
    }
}

// ---------------------------------------------------------------------------
extern "C" void kernel_launch(void* const* d_in, const int* in_sizes, int n_in,
                              void* d_out, int out_size, void* d_ws, size_t ws_size,
                              hipStream_t stream) {
    (void)in_sizes; (void)n_in; (void)out_size; (void)ws_size;

    const float* Q = (const float*)d_in[0];
    const float* K = (const float*)d_in[1];
    const float* V = (const float*)d_in[2];
    const float* past_state = (const float*)d_in[3];
    const float* past_att = (const float*)d_in[4];
    const float* vpos = (const float*)d_in[5];
    const int* mask = (const int*)d_in[6];
    const float* Wq = (const float*)d_in[7];
    const float* Wk = (const float*)d_in[8];
    const float* Wv = (const float*)d_in[9];
    const float* Wpos = (const float*)d_in[10];
    const float* bpos = (const float*)d_in[11];
    const float* Wsigma = (const float*)d_in[12];
    const float* Wrho = (const float*)d_in[13];
    const float* mix_w = (const float*)d_in[14];
    const float* mix_b = (const float*)d_in[15];
    const float* gwi = (const float*)d_in[16];
    const float* gwh = (const float*)d_in[17];
    const float* gbi = (const float*)d_in[18];
    const float* gbh = (const float*)d_in[19];
    const float* Wc = (const float*)d_in[20];
    float* out = (float*)d_out;

    // ---- workspace ----
    char* p = (char*)d_ws;
    const size_t SZB = 8192UL * 512 * 2;
    const size_t SZW = 512UL * 512 * 2;
    bf16* WqT = (bf16*)p;   p += SZW;
    bf16* WkT = (bf16*)p;   p += SZW;
    bf16* WvT = (bf16*)p;   p += SZW;
    bf16* WpT = (bf16*)p;   p += SZW;
    bf16* WpTl = (bf16*)p;  p += SZW;
    bf16* WcT = (bf16*)p;   p += SZW;
    bf16* wih = (bf16*)p;   p += 24576;
    bf16* wil = (bf16*)p;   p += 24576;
    bf16* whh = (bf16*)p;   p += 24576;
    bf16* whl = (bf16*)p;   p += 24576;
    bf16* Qh = (bf16*)p;    p += SZB;
    bf16* Kh = (bf16*)p;    p += SZB;
    bf16* VhT = (bf16*)p;   p += SZB;
    bf16* Xh = (bf16*)p;
    bf16* att = Xh;         p += SZB;
    bf16* Xl = (bf16*)p;    p += SZB;
    unsigned* maskbits = (unsigned*)p;   p += 8192UL * 16 * 4;
    float* mixv = (float*)p;  p += 32768;
    float* stepv = (float*)p; p += 32768;
    float* lenv = (float*)p;  p += 32768;
    float* muv = (float*)p;   p += 262144;
    float* sigv = (float*)p;  p += 262144;

    dim3 blk(256);
    dim3 gProj(128, 8, 1);

    TW tw;
    tw.src[0] = Wq; tw.src[1] = Wk; tw.src[2] = Wv; tw.src[3] = Wpos; tw.src[4] = Wc;
    tw.dst[0] = WqT; tw.dst[1] = WkT; tw.dst[2] = WvT; tw.dst[3] = WpT; tw.dst[4] = WcT;
    tw.dstlo[0] = nullptr; tw.dstlo[1] = nullptr; tw.dstlo[2] = nullptr;
    tw.dstlo[3] = WpTl; tw.dstlo[4] = nullptr;
    trans_w_kernel<<<dim3(64, 5), blk, 0, stream>>>(tw);

    gru_prep_kernel<<<dim3(2), dim3(192), 0, stream>>>(gwi, gwh, wih, wil, whh, whl);

    G3 g;
    g.A[0] = Q; g.A[1] = K; g.A[2] = V;
    g.BT[0] = WqT; g.BT[1] = WkT; g.BT[2] = WvT;
    g.C[0] = Qh; g.C[1] = Kh; g.C[2] = VhT;
    gemm_bt3<<<dim3(128, 8, 3), blk, 0, stream>>>(g);

    gemm_split_hl<<<gProj, blk, 0, stream>>>(Q, WpT, WpTl, bpos, Xh, Xl);

    mix_len_kernel<<<dim3(2048), blk, 0, stream>>>(Q, mask, mix_w, mix_b, mixv, stepv, lenv, maskbits);

    gru_fused_kernel<<<dim3(1024), blk, 0, stream>>>(
        Xh, Xl, past_state, wih, wil, whh, whl, gbi, gbh, past_att, Wsigma, Wrho,
        lenv, stepv, muv, sigv);

    attn_fused_kernel<<<dim3(4096), blk, 0, stream>>>(
        Qh, Kh, VhT, maskbits, vpos, mixv, stepv, muv, sigv, att);

    gemm_out<<<gProj, blk, 0, stream>>>(att, WcT, out);
}